// Round 2
// baseline (6111.663 us; speedup 1.0000x reference)
//
#include <hip/hip_runtime.h>
#include <math.h>

#define N_POL 20000
#define N_COMP 80000
#define NN (N_POL + N_COMP)
#define EE 1000000
#define ETOT (EE + NN)

// ---------- helpers ----------
__device__ __forceinline__ unsigned fenc(float f) {
  unsigned u = __float_as_uint(f);
  return (u >> 31) ? ~u : (u | 0x80000000u);
}
__device__ __forceinline__ float fdec(unsigned u) {
  return (u >> 31) ? __uint_as_float(u & 0x7fffffffu) : __uint_as_float(~u);
}
__device__ __forceinline__ float wave_sum(float v) {
#pragma unroll
  for (int o = 32; o > 0; o >>= 1) v += __shfl_xor(v, o);
  return v;
}
__device__ __forceinline__ unsigned short f2bf(float f) {
  unsigned b = __float_as_uint(f);
  return (unsigned short)((b + 0x7FFFu + ((b >> 16) & 1u)) >> 16);
}
__device__ __forceinline__ float bf2f(unsigned short u) {
  return __uint_as_float(((unsigned)u) << 16);
}

// ---------- K0: tiny precomputes ----------
__global__ void k_pre(const float* W2, const float* as2, const float* ad2,
                      const float* We1, const float* ae1, const float* We2,
                      const float* ae2, float* us2, float* ud2, float* V1, float* V2) {
  int t = threadIdx.x;
  if (t < 256) {
    float s = 0.f, d = 0.f;
    for (int c = 0; c < 128; c++) {
      float w = W2[t * 128 + c];
      s = fmaf(w, as2[c], s);
      d = fmaf(w, ad2[c], d);
    }
    us2[t] = s; ud2[t] = d;
  }
  if (t < 40) {
    int k = t >> 3, h = t & 7;
    float v = 0.f;
    for (int c = 0; c < 32; c++) v = fmaf(We1[k * 256 + h * 32 + c], ae1[h * 32 + c], v);
    V1[k * 8 + h] = v;
  }
  if (t < 5) {
    float v = 0.f;
    for (int c = 0; c < 128; c++) v = fmaf(We2[t * 128 + c], ae2[c], v);
    V2[t] = v;
  }
}

// ---------- init monotonic-encoded -inf for segment max ----------
__global__ void k_init_max(unsigned* max1, unsigned* max2) {
  int id = blockIdx.x * blockDim.x + threadIdx.x;
  const unsigned NEG = 0x007FFFFFu;  // fenc(-inf)
  if (id < NN * 8) max1[id] = NEG;
  if (id < NN) max2[id] = NEG;
}

// ---------- K1: node encoders + LayerNorm (block of 128 per node) ----------
__global__ __launch_bounds__(128) void k_encode(
    const float* pol_feat, const int* state_ids, const int* comp_cat,
    const float* comp_price, const float* Wp, const float* bp,
    const float* state_emb, const float* sector_emb, const float* industry_emb,
    const float* Wc, const float* bc, const float* ln_g, const float* ln_b,
    float* x) {
  int i = blockIdx.x, c = threadIdx.x;
  float v;
  if (i < N_POL) {
    float acc = bp[c];
#pragma unroll
    for (int k = 0; k < 7; k++) acc = fmaf(pol_feat[i * 7 + k], Wp[k * 128 + c], acc);
    v = fmaxf(acc, 0.f) + state_emb[state_ids[i] * 128 + c];
  } else {
    int j = i - N_POL;
    int sc = comp_cat[2 * j], in = comp_cat[2 * j + 1];
    float acc = bc[c];
#pragma unroll
    for (int k = 0; k < 8; k++) acc = fmaf(sector_emb[sc * 8 + k], Wc[k * 128 + c], acc);
#pragma unroll
    for (int k = 0; k < 8; k++) acc = fmaf(industry_emb[in * 8 + k], Wc[(8 + k) * 128 + c], acc);
    acc = fmaf(comp_price[j], Wc[16 * 128 + c], acc);
    v = fmaxf(acc, 0.f);
  }
  __shared__ float red[2];
  int wid = c >> 6, lane = c & 63;
  float s = wave_sum(v);
  if (lane == 0) red[wid] = s;
  __syncthreads();
  float mu = (red[0] + red[1]) * (1.f / 128.f);
  float t0 = v - mu;
  __syncthreads();
  float s2 = wave_sum(t0 * t0);
  if (lane == 0) red[wid] = s2;
  __syncthreads();
  float var = (red[0] + red[1]) * (1.f / 128.f);
  float r = rsqrtf(var + 1e-5f);
  x[(size_t)i * 128 + c] = t0 * r * ln_g[c] + ln_b[c];
}

// ---------- K2: self-loop edge_attr = mean of incoming ----------
__global__ void k_loop_sums(const int* dst, const float* ea, float* cnt, float* sums) {
  int e = blockIdx.x * blockDim.x + threadIdx.x;
  if (e >= EE) return;
  int d = dst[e];
  atomicAdd(&cnt[d], 1.f);
#pragma unroll
  for (int k = 0; k < 5; k++) atomicAdd(&sums[d * 5 + k], ea[(size_t)e * 5 + k]);
}
__global__ void k_loop_div(const float* cnt, float* lattr) {
  int id = blockIdx.x * blockDim.x + threadIdx.x;
  if (id >= NN * 5) return;
  int i = id / 5;
  lattr[id] = lattr[id] / fmaxf(cnt[i], 1.f);
}

// ---------- K3: xw1(bf16) = x@W1 [N,256] + al_s1/al_d1 [N,8] ----------
__global__ __launch_bounds__(256) void k_gemm1(const float* x, const float* W1,
                                               const float* as1, const float* ad1,
                                               unsigned short* xw1, float* al_s1,
                                               float* al_d1) {
  __shared__ float xs[32][128];
  int t = threadIdx.x;
  int base = blockIdx.x * 32;
  for (int idx = t; idx < 32 * 128; idx += 256)
    xs[idx >> 7][idx & 127] = x[(size_t)(base + (idx >> 7)) * 128 + (idx & 127)];
  __syncthreads();
  float acc[32];
#pragma unroll
  for (int r = 0; r < 32; r++) acc[r] = 0.f;
#pragma unroll 4
  for (int k = 0; k < 128; k++) {
    float w = W1[k * 256 + t];
#pragma unroll
    for (int r = 0; r < 32; r++) acc[r] = fmaf(xs[r][k], w, acc[r]);
  }
  float as = as1[t], ad = ad1[t];
#pragma unroll
  for (int r = 0; r < 32; r++) {
    xw1[(size_t)(base + r) * 256 + t] = f2bf(acc[r]);
    float vs = acc[r] * as, vd = acc[r] * ad;
#pragma unroll
    for (int o = 16; o > 0; o >>= 1) { vs += __shfl_xor(vs, o); vd += __shfl_xor(vd, o); }
    if ((t & 31) == 0) {
      al_s1[(base + r) * 8 + (t >> 5)] = vs;
      al_d1[(base + r) * 8 + (t >> 5)] = vd;
    }
  }
}

// ---------- K5: layer-1 segment max (thread per edge) ----------
__global__ void k_max1(const int* src, const int* dst, const float* ea,
                       const float* lattr, const float* al_s1, const float* al_d1,
                       const float* V1, unsigned* max1) {
  int e = blockIdx.x * blockDim.x + threadIdx.x;
  if (e >= ETOT) return;
  int s, d; const float* a;
  if (e < EE) { s = src[e]; d = dst[e]; a = ea + (size_t)e * 5; }
  else { s = d = e - EE; a = lattr + (size_t)(e - EE) * 5; }
  float av[5];
#pragma unroll
  for (int k = 0; k < 5; k++) av[k] = a[k];
#pragma unroll
  for (int h = 0; h < 8; h++) {
    float ale = 0.f;
#pragma unroll
    for (int k = 0; k < 5; k++) ale = fmaf(av[k], V1[k * 8 + h], ale);
    float al = al_s1[s * 8 + h] + al_d1[d * 8 + h] + ale;
    al = al > 0.f ? al : 0.2f * al;
    atomicMax(&max1[d * 8 + h], fenc(al));
  }
}

// ---------- K6: layer-1 exp + denom + weighted accumulate (wave per edge) ----------
__global__ __launch_bounds__(256) void k_acc1(const int* src, const int* dst,
                                              const float* ea, const float* lattr,
                                              const float* al_s1, const float* al_d1,
                                              const float* V1, const unsigned* max1,
                                              const unsigned short* xw1, float* denom1,
                                              float* out1) {
  int gid = blockIdx.x * blockDim.x + threadIdx.x;
  int e = gid >> 6, lane = threadIdx.x & 63;
  if (e >= ETOT) return;
  int s, d;
  if (e < EE) { s = src[e]; d = dst[e]; }
  else { s = d = e - EE; }
  float ex = 0.f;
  if (lane < 8) {
    const float* a = (e < EE) ? ea + (size_t)e * 5 : lattr + (size_t)(e - EE) * 5;
    float ale = 0.f;
#pragma unroll
    for (int k = 0; k < 5; k++) ale = fmaf(a[k], V1[k * 8 + lane], ale);
    float al = al_s1[s * 8 + lane] + al_d1[d * 8 + lane] + ale;
    al = al > 0.f ? al : 0.2f * al;
    ex = __expf(al - fdec(max1[d * 8 + lane]));
    atomicAdd(&denom1[d * 8 + lane], ex);
  }
  float exv = __shfl(ex, lane >> 3);  // head of channels [4*lane,4*lane+3]
  ushort4 xv = ((const ushort4*)(xw1 + (size_t)s * 256))[lane];
  float* o = out1 + (size_t)d * 256 + lane * 4;
  atomicAdd(o + 0, exv * bf2f(xv.x));
  atomicAdd(o + 1, exv * bf2f(xv.y));
  atomicAdd(o + 2, exv * bf2f(xv.z));
  atomicAdd(o + 3, exv * bf2f(xv.w));
}

// ---------- K7: h = elu(out1/denom + b1); al_s2/al_d2 = h . us2/ud2 ----------
__global__ __launch_bounds__(256) void k_fin1(const float* denom1, const float* b1,
                                              const float* us2, const float* ud2,
                                              float* h, float* al_s2, float* al_d2) {
  int i = blockIdx.x, c = threadIdx.x;
  int hd = c >> 5;
  float v = h[(size_t)i * 256 + c] / (denom1[i * 8 + hd] + 1e-16f) + b1[c];
  v = v > 0.f ? v : expm1f(v);
  h[(size_t)i * 256 + c] = v;
  float ps = v * us2[c], pd = v * ud2[c];
  ps = wave_sum(ps); pd = wave_sum(pd);
  __shared__ float rs[4], rd[4];
  int wid = c >> 6, lane = c & 63;
  if (lane == 0) { rs[wid] = ps; rd[wid] = pd; }
  __syncthreads();
  if (c == 0) {
    al_s2[i] = rs[0] + rs[1] + rs[2] + rs[3];
    al_d2[i] = rd[0] + rd[1] + rd[2] + rd[3];
  }
}

// ---------- K8: xw2 = h@W2 [N,128] ----------
__global__ __launch_bounds__(128) void k_gemm2(const float* h, const float* W2, float* xw2) {
  __shared__ float hs[32][256];
  int t = threadIdx.x;
  int base = blockIdx.x * 32;
  for (int idx = t; idx < 32 * 256; idx += 128)
    hs[idx >> 8][idx & 255] = h[(size_t)(base + (idx >> 8)) * 256 + (idx & 255)];
  __syncthreads();
  float acc[32];
#pragma unroll
  for (int r = 0; r < 32; r++) acc[r] = 0.f;
#pragma unroll 4
  for (int k = 0; k < 256; k++) {
    float w = W2[k * 128 + t];
#pragma unroll
    for (int r = 0; r < 32; r++) acc[r] = fmaf(hs[r][k], w, acc[r]);
  }
#pragma unroll
  for (int r = 0; r < 32; r++) xw2[(size_t)(base + r) * 128 + t] = acc[r];
}

// ---------- K10: layer-2 segment max ----------
__global__ void k_max2(const int* src, const int* dst, const float* ea,
                       const float* lattr, const float* al_s2, const float* al_d2,
                       const float* V2, unsigned* max2) {
  int e = blockIdx.x * blockDim.x + threadIdx.x;
  if (e >= ETOT) return;
  int s, d; const float* a;
  if (e < EE) { s = src[e]; d = dst[e]; a = ea + (size_t)e * 5; }
  else { s = d = e - EE; a = lattr + (size_t)(e - EE) * 5; }
  float ale = 0.f;
#pragma unroll
  for (int k = 0; k < 5; k++) ale = fmaf(a[k], V2[k], ale);
  float al = al_s2[s] + al_d2[d] + ale;
  al = al > 0.f ? al : 0.2f * al;
  atomicMax(&max2[d], fenc(al));
}

// ---------- K11: layer-2 exp + denom + weighted accumulate (wave per edge) ----------
__global__ __launch_bounds__(256) void k_acc2(const int* src, const int* dst,
                                              const float* ea, const float* lattr,
                                              const float* al_s2, const float* al_d2,
                                              const float* V2, const unsigned* max2,
                                              const float* xw2, float* denom2, float* out) {
  int gid = blockIdx.x * blockDim.x + threadIdx.x;
  int e = gid >> 6, lane = threadIdx.x & 63;
  if (e >= ETOT) return;
  int s, d;
  if (e < EE) { s = src[e]; d = dst[e]; }
  else { s = d = e - EE; }
  float ex = 0.f;
  if (lane == 0) {
    const float* a = (e < EE) ? ea + (size_t)e * 5 : lattr + (size_t)(e - EE) * 5;
    float ale = 0.f;
#pragma unroll
    for (int k = 0; k < 5; k++) ale = fmaf(a[k], V2[k], ale);
    float al = al_s2[s] + al_d2[d] + ale;
    al = al > 0.f ? al : 0.2f * al;
    ex = __expf(al - fdec(max2[d]));
    atomicAdd(&denom2[d], ex);
  }
  float exv = __shfl(ex, 0);
  float2 xv = ((const float2*)(xw2 + (size_t)s * 128))[lane];
  float* o = out + (size_t)d * 128 + lane * 2;
  atomicAdd(o + 0, exv * xv.x);
  atomicAdd(o + 1, exv * xv.y);
}

// ---------- K12: final normalize + bias ----------
__global__ void k_fin2(const float* denom2, const float* b2, float* out) {
  int id = blockIdx.x * blockDim.x + threadIdx.x;
  if (id >= NN * 128) return;
  int i = id >> 7, c = id & 127;
  out[id] = out[id] / (denom2[i] + 1e-16f) + b2[c];
}

extern "C" void kernel_launch(void* const* d_in, const int* in_sizes, int n_in,
                              void* d_out, int out_size, void* d_ws, size_t ws_size,
                              hipStream_t stream) {
  const float* pol_feat = (const float*)d_in[0];
  const int* state_ids = (const int*)d_in[1];
  const int* comp_cat = (const int*)d_in[2];
  const float* comp_price = (const float*)d_in[3];
  const int* edge_index = (const int*)d_in[4];
  const float* edge_attr = (const float*)d_in[5];
  const float* Wp = (const float*)d_in[6];
  const float* bp = (const float*)d_in[7];
  const float* state_emb = (const float*)d_in[8];
  const float* sector_emb = (const float*)d_in[9];
  const float* industry_emb = (const float*)d_in[10];
  const float* Wc = (const float*)d_in[11];
  const float* bc = (const float*)d_in[12];
  const float* ln_g = (const float*)d_in[13];
  const float* ln_b = (const float*)d_in[14];
  const float* W1 = (const float*)d_in[15];
  const float* as1 = (const float*)d_in[16];
  const float* ad1 = (const float*)d_in[17];
  const float* We1 = (const float*)d_in[18];
  const float* ae1 = (const float*)d_in[19];
  const float* b1 = (const float*)d_in[20];
  const float* W2 = (const float*)d_in[21];
  const float* as2 = (const float*)d_in[22];
  const float* ad2 = (const float*)d_in[23];
  const float* We2 = (const float*)d_in[24];
  const float* ae2 = (const float*)d_in[25];
  const float* b2 = (const float*)d_in[26];
  const int* srcv = edge_index;
  const int* dstv = edge_index + EE;
  float* out = (float*)d_out;

  // ---- workspace layout (aliased; peak ~163 MiB) ----
  size_t off = 0;
  auto alloc = [&](size_t nbytes) -> char* {
    char* p = (char*)d_ws + off;
    off += ((nbytes + 255) & ~(size_t)255);
    return p;
  };
  // region A: xw1 (bf16, N*256*2 = 51.2MB); reused as xw2 (f32, N*128*4 = 51.2MB)
  char* regA = alloc((size_t)NN * 256 * 2);
  // region B: out1/h (f32, N*256*4 = 102.4MB); x (f32, N*128*4) occupies first half
  char* regB = alloc((size_t)NN * 256 * 4);
  unsigned short* xw1 = (unsigned short*)regA;
  float* xw2 = (float*)regA;
  float* out1 = (float*)regB;  // memset AFTER gemm1 (x aliases its first half)
  float* x = (float*)regB;
  float* al_s1 = (float*)alloc((size_t)NN * 8 * 4);
  float* al_d1 = (float*)alloc((size_t)NN * 8 * 4);
  float* lcnt = (float*)alloc((size_t)NN * 4);
  float* lattr = (float*)alloc((size_t)NN * 5 * 4);
  float* denom1 = (float*)alloc((size_t)NN * 8 * 4);
  unsigned* max1 = (unsigned*)alloc((size_t)NN * 8 * 4);
  float* al_s2 = (float*)alloc((size_t)NN * 4);
  float* al_d2 = (float*)alloc((size_t)NN * 4);
  float* denom2 = (float*)alloc((size_t)NN * 4);
  unsigned* max2 = (unsigned*)alloc((size_t)NN * 4);
  float* us2 = (float*)alloc(256 * 4);
  float* ud2 = (float*)alloc(256 * 4);
  float* V1 = (float*)alloc(64 * 4);
  float* V2 = (float*)alloc(8 * 4);

  hipMemsetAsync(lcnt, 0, (size_t)NN * 4, stream);
  hipMemsetAsync(lattr, 0, (size_t)NN * 5 * 4, stream);
  hipMemsetAsync(denom1, 0, (size_t)NN * 8 * 4, stream);
  hipMemsetAsync(denom2, 0, (size_t)NN * 4, stream);
  hipMemsetAsync(d_out, 0, (size_t)NN * 128 * 4, stream);

  k_pre<<<1, 256, 0, stream>>>(W2, as2, ad2, We1, ae1, We2, ae2, us2, ud2, V1, V2);
  k_init_max<<<(NN * 8 + 255) / 256, 256, 0, stream>>>(max1, max2);
  k_encode<<<NN, 128, 0, stream>>>(pol_feat, state_ids, comp_cat, comp_price, Wp, bp,
                                   state_emb, sector_emb, industry_emb, Wc, bc, ln_g,
                                   ln_b, x);
  k_loop_sums<<<(EE + 255) / 256, 256, 0, stream>>>(dstv, edge_attr, lcnt, lattr);
  k_loop_div<<<(NN * 5 + 255) / 256, 256, 0, stream>>>(lcnt, lattr);
  k_gemm1<<<NN / 32, 256, 0, stream>>>(x, W1, as1, ad1, xw1, al_s1, al_d1);
  // x is dead now; out1 aliases it — zero the full region before accumulation
  hipMemsetAsync(out1, 0, (size_t)NN * 256 * 4, stream);
  k_max1<<<(ETOT + 255) / 256, 256, 0, stream>>>(srcv, dstv, edge_attr, lattr, al_s1,
                                                 al_d1, V1, max1);
  k_acc1<<<ETOT / 4, 256, 0, stream>>>(srcv, dstv, edge_attr, lattr, al_s1, al_d1, V1,
                                       max1, xw1, denom1, out1);
  k_fin1<<<NN, 256, 0, stream>>>(denom1, b1, us2, ud2, out1, al_s2, al_d2);
  // xw1 dead now; xw2 aliases region A
  k_gemm2<<<NN / 32, 128, 0, stream>>>(out1, W2, xw2);
  k_max2<<<(ETOT + 255) / 256, 256, 0, stream>>>(srcv, dstv, edge_attr, lattr, al_s2,
                                                 al_d2, V2, max2);
  k_acc2<<<ETOT / 4, 256, 0, stream>>>(srcv, dstv, edge_attr, lattr, al_s2, al_d2, V2,
                                       max2, xw2, denom2, out);
  k_fin2<<<(NN * 128 + 255) / 256, 256, 0, stream>>>(denom2, b2, out);
}

// Round 3
// 1196.893 us; speedup vs baseline: 5.1063x; 5.1063x over previous
//
#include <hip/hip_runtime.h>
#include <math.h>

#define N_POL 20000
#define N_COMP 80000
#define NN (N_POL + N_COMP)
#define EE 1000000
#define NB1 ((NN + 1023) / 1024)  // scan blocks

// ---------- helpers ----------
__device__ __forceinline__ float wave_sum(float v) {
#pragma unroll
  for (int o = 32; o > 0; o >>= 1) v += __shfl_xor(v, o);
  return v;
}
__device__ __forceinline__ unsigned short f2bf(float f) {
  unsigned b = __float_as_uint(f);
  return (unsigned short)((b + 0x7FFFu + ((b >> 16) & 1u)) >> 16);
}
__device__ __forceinline__ float bf2f(unsigned short u) {
  return __uint_as_float(((unsigned)u) << 16);
}

// ---------- K0: tiny precomputes ----------
// us2[k]=W2[k,:]·as2 ; ud2[k]=W2[k,:]·ad2 ; V1[k][h]=We1[k,h*32:]·ae1[h,:] ; V2[k]=We2[k,:]·ae2
__global__ void k_pre(const float* W2, const float* as2, const float* ad2,
                      const float* We1, const float* ae1, const float* We2,
                      const float* ae2, float* us2, float* ud2, float* V1, float* V2) {
  int t = threadIdx.x;
  if (t < 256) {
    float s = 0.f, d = 0.f;
    for (int c = 0; c < 128; c++) {
      float w = W2[t * 128 + c];
      s = fmaf(w, as2[c], s);
      d = fmaf(w, ad2[c], d);
    }
    us2[t] = s; ud2[t] = d;
  }
  if (t < 40) {
    int k = t >> 3, h = t & 7;
    float v = 0.f;
    for (int c = 0; c < 32; c++) v = fmaf(We1[k * 256 + h * 32 + c], ae1[h * 32 + c], v);
    V1[k * 8 + h] = v;
  }
  if (t < 5) {
    float v = 0.f;
    for (int c = 0; c < 128; c++) v = fmaf(We2[t * 128 + c], ae2[c], v);
    V2[t] = v;
  }
}

// ---------- K1: node encoders + LayerNorm ----------
__global__ __launch_bounds__(128) void k_encode(
    const float* pol_feat, const int* state_ids, const int* comp_cat,
    const float* comp_price, const float* Wp, const float* bp,
    const float* state_emb, const float* sector_emb, const float* industry_emb,
    const float* Wc, const float* bc, const float* ln_g, const float* ln_b,
    float* x) {
  int i = blockIdx.x, c = threadIdx.x;
  float v;
  if (i < N_POL) {
    float acc = bp[c];
#pragma unroll
    for (int k = 0; k < 7; k++) acc = fmaf(pol_feat[i * 7 + k], Wp[k * 128 + c], acc);
    v = fmaxf(acc, 0.f) + state_emb[state_ids[i] * 128 + c];
  } else {
    int j = i - N_POL;
    int sc = comp_cat[2 * j], in = comp_cat[2 * j + 1];
    float acc = bc[c];
#pragma unroll
    for (int k = 0; k < 8; k++) acc = fmaf(sector_emb[sc * 8 + k], Wc[k * 128 + c], acc);
#pragma unroll
    for (int k = 0; k < 8; k++) acc = fmaf(industry_emb[in * 8 + k], Wc[(8 + k) * 128 + c], acc);
    acc = fmaf(comp_price[j], Wc[16 * 128 + c], acc);
    v = fmaxf(acc, 0.f);
  }
  __shared__ float red[2];
  int wid = c >> 6, lane = c & 63;
  float s = wave_sum(v);
  if (lane == 0) red[wid] = s;
  __syncthreads();
  float mu = (red[0] + red[1]) * (1.f / 128.f);
  float t0 = v - mu;
  __syncthreads();
  float s2 = wave_sum(t0 * t0);
  if (lane == 0) red[wid] = s2;
  __syncthreads();
  float var = (red[0] + red[1]) * (1.f / 128.f);
  float r = rsqrtf(var + 1e-5f);
  x[(size_t)i * 128 + c] = t0 * r * ln_g[c] + ln_b[c];
}

// ---------- CSR build ----------
__global__ void k_hist(const int* dst, unsigned* hist) {
  int e = blockIdx.x * blockDim.x + threadIdx.x;
  if (e < EE) atomicAdd(&hist[dst[e]], 1u);
}
__global__ __launch_bounds__(1024) void k_scan1(const unsigned* hist, unsigned* rowptr,
                                                unsigned* part) {
  __shared__ unsigned sc[1024];
  int t = threadIdx.x;
  int i = blockIdx.x * 1024 + t;
  unsigned v = (i < NN) ? hist[i] : 0u;
  sc[t] = v;
  __syncthreads();
  for (int o = 1; o < 1024; o <<= 1) {
    unsigned add = (t >= o) ? sc[t - o] : 0u;
    __syncthreads();
    sc[t] += add;
    __syncthreads();
  }
  if (i < NN) rowptr[i] = sc[t] - v;  // exclusive
  if (t == 1023) part[blockIdx.x] = sc[1023];
}
__global__ void k_scan2(unsigned* part) {
  if (threadIdx.x == 0) {
    unsigned run = 0;
    for (int b = 0; b < NB1; b++) { unsigned t = part[b]; part[b] = run; run += t; }
  }
}
__global__ void k_scan3(unsigned* rowptr, const unsigned* part, unsigned* cursor) {
  int i = blockIdx.x * blockDim.x + threadIdx.x;
  if (i < NN) {
    unsigned r = rowptr[i] + part[i >> 10];
    rowptr[i] = r;
    cursor[i] = r;
  }
  if (i == 0) rowptr[NN] = EE;
}
__global__ void k_scatter(const int* dst, unsigned* cursor, int* eidx) {
  int e = blockIdx.x * blockDim.x + threadIdx.x;
  if (e >= EE) return;
  unsigned pos = atomicAdd(&cursor[dst[e]], 1u);
  eidx[pos] = e;
}

// ---------- K3: xw1(bf16) = x@W1 [N,256] + al_s1/al_d1 [N,8] ----------
__global__ __launch_bounds__(256) void k_gemm1(const float* x, const float* W1,
                                               const float* as1, const float* ad1,
                                               unsigned short* xw1, float* al_s1,
                                               float* al_d1) {
  __shared__ float xs[32][128];
  int t = threadIdx.x;
  int base = blockIdx.x * 32;
  for (int idx = t; idx < 32 * 128; idx += 256)
    xs[idx >> 7][idx & 127] = x[(size_t)(base + (idx >> 7)) * 128 + (idx & 127)];
  __syncthreads();
  float acc[32];
#pragma unroll
  for (int r = 0; r < 32; r++) acc[r] = 0.f;
#pragma unroll 4
  for (int k = 0; k < 128; k++) {
    float w = W1[k * 256 + t];
#pragma unroll
    for (int r = 0; r < 32; r++) acc[r] = fmaf(xs[r][k], w, acc[r]);
  }
  float as = as1[t], ad = ad1[t];
#pragma unroll
  for (int r = 0; r < 32; r++) {
    xw1[(size_t)(base + r) * 256 + t] = f2bf(acc[r]);
    float vs = acc[r] * as, vd = acc[r] * ad;
#pragma unroll
    for (int o = 16; o > 0; o >>= 1) { vs += __shfl_xor(vs, o); vd += __shfl_xor(vd, o); }
    if ((t & 31) == 0) {
      al_s1[(base + r) * 8 + (t >> 5)] = vs;
      al_d1[(base + r) * 8 + (t >> 5)] = vd;
    }
  }
}

// ---------- K4: layer-1 GAT, wave per dst node, online softmax ----------
__global__ __launch_bounds__(256) void k_gat1(
    const unsigned* rowptr, const int* eidx, const int* srcv, const float* ea_g,
    const float* al_s1, const float* al_d1, const float* V1,
    const unsigned short* xw1, const float* b1, const float* us2, const float* ud2,
    float* h, float* al_s2, float* al_d2, float* lattr) {
  int w = threadIdx.x >> 6, lane = threadIdx.x & 63;
  int i = blockIdx.x * 4 + w;
  if (i >= NN) return;
  int r0 = rowptr[i], r1 = rowptr[i + 1];
  float v1k[5];
  float ald = 0.f, als_self = 0.f;
  if (lane < 8) {
#pragma unroll
    for (int k = 0; k < 5; k++) v1k[k] = V1[k * 8 + lane];
    ald = al_d1[i * 8 + lane];
    als_self = al_s1[i * 8 + lane];
  }
  int head = lane >> 3;
  float m = -1e30f, l = 0.f;
  float a0 = 0.f, a1 = 0.f, a2 = 0.f, a3 = 0.f;
  float sea = 0.f;  // lanes 0..4 accumulate ea sum
  for (int j = r0; j < r1; j++) {
    int e = eidx[j];
    int s = srcv[e];
    float al = 0.f;
    if (lane < 8) {
      float ale = 0.f;
#pragma unroll
      for (int k = 0; k < 5; k++) ale = fmaf(ea_g[(size_t)e * 5 + k], v1k[k], ale);
      al = al_s1[s * 8 + lane] + ald + ale;
      al = al > 0.f ? al : 0.2f * al;
    }
    if (lane < 5) sea += ea_g[(size_t)e * 5 + lane];
    float myal = __shfl(al, head);
    float mn = fmaxf(m, myal);
    float scale = __expf(m - mn);
    float p = __expf(myal - mn);
    m = mn;
    l = l * scale + p;
    ushort4 xv = ((const ushort4*)(xw1 + (size_t)s * 256))[lane];
    a0 = fmaf(p, bf2f(xv.x), a0 * scale);
    a1 = fmaf(p, bf2f(xv.y), a1 * scale);
    a2 = fmaf(p, bf2f(xv.z), a2 * scale);
    a3 = fmaf(p, bf2f(xv.w), a3 * scale);
  }
  // self-loop: edge_attr = mean of incoming (0 if none)
  float inv = 1.f / fmaxf((float)(r1 - r0), 1.f);
  float la0 = __shfl(sea, 0) * inv, la1 = __shfl(sea, 1) * inv, la2 = __shfl(sea, 2) * inv,
        la3 = __shfl(sea, 3) * inv, la4 = __shfl(sea, 4) * inv;
  if (lane < 5) lattr[i * 5 + lane] = sea * inv;
  float al = 0.f;
  if (lane < 8) {
    float ale = fmaf(la0, v1k[0], fmaf(la1, v1k[1], fmaf(la2, v1k[2],
                fmaf(la3, v1k[3], la4 * v1k[4]))));
    al = als_self + ald + ale;
    al = al > 0.f ? al : 0.2f * al;
  }
  float myal = __shfl(al, head);
  float mn = fmaxf(m, myal);
  float scale = __expf(m - mn);
  float p = __expf(myal - mn);
  l = l * scale + p;
  ushort4 xv = ((const ushort4*)(xw1 + (size_t)i * 256))[lane];
  a0 = fmaf(p, bf2f(xv.x), a0 * scale);
  a1 = fmaf(p, bf2f(xv.y), a1 * scale);
  a2 = fmaf(p, bf2f(xv.z), a2 * scale);
  a3 = fmaf(p, bf2f(xv.w), a3 * scale);
  // finalize: /l + b1, elu
  float invl = 1.f / (l + 1e-16f);
  float4 bv = ((const float4*)b1)[lane];
  float v0 = a0 * invl + bv.x, v1 = a1 * invl + bv.y;
  float v2 = a2 * invl + bv.z, v3 = a3 * invl + bv.w;
  v0 = v0 > 0.f ? v0 : expm1f(v0);
  v1 = v1 > 0.f ? v1 : expm1f(v1);
  v2 = v2 > 0.f ? v2 : expm1f(v2);
  v3 = v3 > 0.f ? v3 : expm1f(v3);
  float4 hv = {v0, v1, v2, v3};
  ((float4*)(h + (size_t)i * 256))[lane] = hv;
  // layer-2 logit pieces
  float4 uv = ((const float4*)us2)[lane];
  float4 dv = ((const float4*)ud2)[lane];
  float ps = v0 * uv.x + v1 * uv.y + v2 * uv.z + v3 * uv.w;
  float pd = v0 * dv.x + v1 * dv.y + v2 * dv.z + v3 * dv.w;
  ps = wave_sum(ps);
  pd = wave_sum(pd);
  if (lane == 0) { al_s2[i] = ps; al_d2[i] = pd; }
}

// ---------- K5: xw2 = h@W2 [N,128] ----------
__global__ __launch_bounds__(128) void k_gemm2(const float* h, const float* W2, float* xw2) {
  __shared__ float hs[32][256];
  int t = threadIdx.x;
  int base = blockIdx.x * 32;
  for (int idx = t; idx < 32 * 256; idx += 128)
    hs[idx >> 8][idx & 255] = h[(size_t)(base + (idx >> 8)) * 256 + (idx & 255)];
  __syncthreads();
  float acc[32];
#pragma unroll
  for (int r = 0; r < 32; r++) acc[r] = 0.f;
#pragma unroll 4
  for (int k = 0; k < 256; k++) {
    float w = W2[k * 128 + t];
#pragma unroll
    for (int r = 0; r < 32; r++) acc[r] = fmaf(hs[r][k], w, acc[r]);
  }
#pragma unroll
  for (int r = 0; r < 32; r++) xw2[(size_t)(base + r) * 128 + t] = acc[r];
}

// ---------- K6: layer-2 GAT, wave per dst node, online softmax ----------
__global__ __launch_bounds__(256) void k_gat2(
    const unsigned* rowptr, const int* eidx, const int* srcv, const float* ea_g,
    const float* al_s2, const float* al_d2, const float* V2, const float* lattr,
    const float* xw2, const float* b2, float* out) {
  int w = threadIdx.x >> 6, lane = threadIdx.x & 63;
  int i = blockIdx.x * 4 + w;
  if (i >= NN) return;
  int r0 = rowptr[i], r1 = rowptr[i + 1];
  float v2k[5];
#pragma unroll
  for (int k = 0; k < 5; k++) v2k[k] = V2[k];
  float ald = al_d2[i];
  float m = -1e30f, l = 0.f, a0 = 0.f, a1 = 0.f;
  for (int j = r0; j < r1; j++) {
    int e = eidx[j];
    int s = srcv[e];
    float ale = 0.f;
#pragma unroll
    for (int k = 0; k < 5; k++) ale = fmaf(ea_g[(size_t)e * 5 + k], v2k[k], ale);
    float al = al_s2[s] + ald + ale;
    al = al > 0.f ? al : 0.2f * al;
    float mn = fmaxf(m, al);
    float scale = __expf(m - mn);
    float p = __expf(al - mn);
    m = mn;
    l = l * scale + p;
    float2 xv = ((const float2*)(xw2 + (size_t)s * 128))[lane];
    a0 = fmaf(p, xv.x, a0 * scale);
    a1 = fmaf(p, xv.y, a1 * scale);
  }
  // self loop
  float ale = 0.f;
#pragma unroll
  for (int k = 0; k < 5; k++) ale = fmaf(lattr[i * 5 + k], v2k[k], ale);
  float al = al_s2[i] + ald + ale;
  al = al > 0.f ? al : 0.2f * al;
  float mn = fmaxf(m, al);
  float scale = __expf(m - mn);
  float p = __expf(al - mn);
  l = l * scale + p;
  float2 xv = ((const float2*)(xw2 + (size_t)i * 128))[lane];
  a0 = fmaf(p, xv.x, a0 * scale);
  a1 = fmaf(p, xv.y, a1 * scale);
  float invl = 1.f / (l + 1e-16f);
  float2 bv = ((const float2*)b2)[lane];
  float2 ov = {a0 * invl + bv.x, a1 * invl + bv.y};
  ((float2*)(out + (size_t)i * 128))[lane] = ov;
}

extern "C" void kernel_launch(void* const* d_in, const int* in_sizes, int n_in,
                              void* d_out, int out_size, void* d_ws, size_t ws_size,
                              hipStream_t stream) {
  const float* pol_feat = (const float*)d_in[0];
  const int* state_ids = (const int*)d_in[1];
  const int* comp_cat = (const int*)d_in[2];
  const float* comp_price = (const float*)d_in[3];
  const int* edge_index = (const int*)d_in[4];
  const float* edge_attr = (const float*)d_in[5];
  const float* Wp = (const float*)d_in[6];
  const float* bp = (const float*)d_in[7];
  const float* state_emb = (const float*)d_in[8];
  const float* sector_emb = (const float*)d_in[9];
  const float* industry_emb = (const float*)d_in[10];
  const float* Wc = (const float*)d_in[11];
  const float* bc = (const float*)d_in[12];
  const float* ln_g = (const float*)d_in[13];
  const float* ln_b = (const float*)d_in[14];
  const float* W1 = (const float*)d_in[15];
  const float* as1 = (const float*)d_in[16];
  const float* ad1 = (const float*)d_in[17];
  const float* We1 = (const float*)d_in[18];
  const float* ae1 = (const float*)d_in[19];
  const float* b1 = (const float*)d_in[20];
  const float* W2 = (const float*)d_in[21];
  const float* as2 = (const float*)d_in[22];
  const float* ad2 = (const float*)d_in[23];
  const float* We2 = (const float*)d_in[24];
  const float* ae2 = (const float*)d_in[25];
  const float* b2 = (const float*)d_in[26];
  const int* srcv = edge_index;
  const int* dstv = edge_index + EE;
  float* out = (float*)d_out;

  // ---- workspace layout (aliased; peak ~168 MiB) ----
  size_t off = 0;
  auto alloc = [&](size_t nbytes) -> char* {
    char* p = (char*)d_ws + off;
    off += ((nbytes + 255) & ~(size_t)255);
    return p;
  };
  // region A: xw1 (bf16, N*256*2) reused later as xw2 (f32, N*128*4) — same size
  char* regA = alloc((size_t)NN * 256 * 2);
  // region B: h (f32, N*256*4); x (f32, N*128*4) occupies its first half (dead after gemm1)
  char* regB = alloc((size_t)NN * 256 * 4);
  unsigned short* xw1 = (unsigned short*)regA;
  float* xw2 = (float*)regA;
  float* h = (float*)regB;
  float* x = (float*)regB;
  float* al_s1 = (float*)alloc((size_t)NN * 8 * 4);
  float* al_d1 = (float*)alloc((size_t)NN * 8 * 4);
  float* al_s2 = (float*)alloc((size_t)NN * 4);
  float* al_d2 = (float*)alloc((size_t)NN * 4);
  float* lattr = (float*)alloc((size_t)NN * 5 * 4);
  float* us2 = (float*)alloc(256 * 4);
  float* ud2 = (float*)alloc(256 * 4);
  float* V1 = (float*)alloc(64 * 4);
  float* V2 = (float*)alloc(8 * 4);
  unsigned* hist = (unsigned*)alloc((size_t)NN * 4);
  unsigned* rowptr = (unsigned*)alloc((size_t)(NN + 1) * 4);
  unsigned* cursor = (unsigned*)alloc((size_t)NN * 4);
  unsigned* part = (unsigned*)alloc((size_t)NB1 * 4);
  int* eidx = (int*)alloc((size_t)EE * 4);

  hipMemsetAsync(hist, 0, (size_t)NN * 4, stream);

  k_pre<<<1, 256, 0, stream>>>(W2, as2, ad2, We1, ae1, We2, ae2, us2, ud2, V1, V2);
  k_encode<<<NN, 128, 0, stream>>>(pol_feat, state_ids, comp_cat, comp_price, Wp, bp,
                                   state_emb, sector_emb, industry_emb, Wc, bc, ln_g,
                                   ln_b, x);
  k_hist<<<(EE + 255) / 256, 256, 0, stream>>>(dstv, hist);
  k_scan1<<<NB1, 1024, 0, stream>>>(hist, rowptr, part);
  k_scan2<<<1, 64, 0, stream>>>(part);
  k_scan3<<<(NN + 255) / 256, 256, 0, stream>>>(rowptr, part, cursor);
  k_scatter<<<(EE + 255) / 256, 256, 0, stream>>>(dstv, cursor, eidx);
  k_gemm1<<<NN / 32, 256, 0, stream>>>(x, W1, as1, ad1, xw1, al_s1, al_d1);
  k_gat1<<<NN / 4, 256, 0, stream>>>(rowptr, eidx, srcv, edge_attr, al_s1, al_d1, V1,
                                     xw1, b1, us2, ud2, h, al_s2, al_d2, lattr);
  k_gemm2<<<NN / 32, 128, 0, stream>>>(h, W2, xw2);
  k_gat2<<<NN / 4, 256, 0, stream>>>(rowptr, eidx, srcv, edge_attr, al_s2, al_d2, V2,
                                     lattr, xw2, b2, out);
}

// Round 4
// 796.139 us; speedup vs baseline: 7.6766x; 1.5034x over previous
//
#include <hip/hip_runtime.h>
#include <math.h>

#define N_POL 20000
#define N_COMP 80000
#define NN (N_POL + N_COMP)
#define EE 1000000
#define NB1 ((NN + 1023) / 1024)  // scan blocks

typedef short bf16x8 __attribute__((ext_vector_type(8)));
typedef float f32x4 __attribute__((ext_vector_type(4)));

// ---------- helpers ----------
__device__ __forceinline__ float wave_sum(float v) {
#pragma unroll
  for (int o = 32; o > 0; o >>= 1) v += __shfl_xor(v, o);
  return v;
}
__device__ __forceinline__ unsigned short f2bf(float f) {
  unsigned b = __float_as_uint(f);
  return (unsigned short)((b + 0x7FFFu + ((b >> 16) & 1u)) >> 16);
}
__device__ __forceinline__ float bf2f(unsigned short u) {
  return __uint_as_float(((unsigned)u) << 16);
}

// ---------- K0: tiny precomputes ----------
// us2[k]=W2[k,:]·as2 ; ud2[k]=W2[k,:]·ad2 ; V1[k][h]=We1[k,h*32:]·ae1[h,:] ; V2[k]=We2[k,:]·ae2
// ws1h[k][h]=sum_c W1[k,h*32+c]*as1[h*32+c] ; wd1h likewise with ad1
__global__ void k_pre(const float* W2, const float* as2, const float* ad2,
                      const float* We1, const float* ae1, const float* We2,
                      const float* ae2, const float* W1, const float* as1,
                      const float* ad1, float* us2, float* ud2, float* V1, float* V2,
                      float* ws1h, float* wd1h) {
  int t = threadIdx.x;
  if (t < 256) {
    float s = 0.f, d = 0.f;
    for (int c = 0; c < 128; c++) {
      float w = W2[t * 128 + c];
      s = fmaf(w, as2[c], s);
      d = fmaf(w, ad2[c], d);
    }
    us2[t] = s; ud2[t] = d;
  }
  if (t < 128) {
    for (int h = 0; h < 8; h++) {
      float s = 0.f, d = 0.f;
      for (int c = 0; c < 32; c++) {
        float w = W1[t * 256 + h * 32 + c];
        s = fmaf(w, as1[h * 32 + c], s);
        d = fmaf(w, ad1[h * 32 + c], d);
      }
      ws1h[t * 8 + h] = s;
      wd1h[t * 8 + h] = d;
    }
  }
  if (t < 40) {
    int k = t >> 3, h = t & 7;
    float v = 0.f;
    for (int c = 0; c < 32; c++) v = fmaf(We1[k * 256 + h * 32 + c], ae1[h * 32 + c], v);
    V1[k * 8 + h] = v;
  }
  if (t < 5) {
    float v = 0.f;
    for (int c = 0; c < 128; c++) v = fmaf(We2[t * 128 + c], ae2[c], v);
    V2[t] = v;
  }
}

// ---------- weight transposes to [N][K] bf16 ----------
__global__ void k_prew(const float* W1, const float* W2, unsigned short* W1t,
                       unsigned short* W2t) {
  int id = blockIdx.x * 256 + threadIdx.x;
  if (id < 32768) {
    int n = id >> 7, k = id & 127;
    W1t[id] = f2bf(W1[k * 256 + n]);
  } else {
    int id2 = id - 32768;
    int n = id2 >> 8, k = id2 & 255;
    W2t[id2] = f2bf(W2[k * 128 + n]);
  }
}

// ---------- K1: node encoders + LayerNorm + layer-1 logit pieces ----------
__global__ __launch_bounds__(128) void k_encode(
    const float* pol_feat, const int* state_ids, const int* comp_cat,
    const float* comp_price, const float* Wp, const float* bp,
    const float* state_emb, const float* sector_emb, const float* industry_emb,
    const float* Wc, const float* bc, const float* ln_g, const float* ln_b,
    const float* ws1h, const float* wd1h, unsigned short* x, float* al_s1,
    float* al_d1) {
  int i = blockIdx.x, c = threadIdx.x;
  float v;
  if (i < N_POL) {
    float acc = bp[c];
#pragma unroll
    for (int k = 0; k < 7; k++) acc = fmaf(pol_feat[i * 7 + k], Wp[k * 128 + c], acc);
    v = fmaxf(acc, 0.f) + state_emb[state_ids[i] * 128 + c];
  } else {
    int j = i - N_POL;
    int sc = comp_cat[2 * j], in = comp_cat[2 * j + 1];
    float acc = bc[c];
#pragma unroll
    for (int k = 0; k < 8; k++) acc = fmaf(sector_emb[sc * 8 + k], Wc[k * 128 + c], acc);
#pragma unroll
    for (int k = 0; k < 8; k++) acc = fmaf(industry_emb[in * 8 + k], Wc[(8 + k) * 128 + c], acc);
    acc = fmaf(comp_price[j], Wc[16 * 128 + c], acc);
    v = fmaxf(acc, 0.f);
  }
  __shared__ float red[2];
  __shared__ float xs[128];
  int wid = c >> 6, lane = c & 63;
  float s = wave_sum(v);
  if (lane == 0) red[wid] = s;
  __syncthreads();
  float mu = (red[0] + red[1]) * (1.f / 128.f);
  float t0 = v - mu;
  __syncthreads();
  float s2 = wave_sum(t0 * t0);
  if (lane == 0) red[wid] = s2;
  __syncthreads();
  float var = (red[0] + red[1]) * (1.f / 128.f);
  float r = rsqrtf(var + 1e-5f);
  float xf = t0 * r * ln_g[c] + ln_b[c];
  x[(size_t)i * 128 + c] = f2bf(xf);
  xs[c] = xf;
  __syncthreads();
  if (c < 16) {
    int hh = c & 7;
    const float* wv = (c < 8) ? ws1h : wd1h;
    float dot = 0.f;
    for (int k2 = 0; k2 < 128; k2++) dot = fmaf(xs[k2], wv[k2 * 8 + hh], dot);
    if (c < 8) al_s1[i * 8 + hh] = dot;
    else al_d1[i * 8 + hh] = dot;
  }
}

// ---------- CSR build ----------
__global__ void k_hist(const int* dst, unsigned* hist) {
  int e = blockIdx.x * blockDim.x + threadIdx.x;
  if (e < EE) atomicAdd(&hist[dst[e]], 1u);
}
__global__ __launch_bounds__(1024) void k_scan1(const unsigned* hist, unsigned* rowptr,
                                                unsigned* part) {
  __shared__ unsigned sc[1024];
  int t = threadIdx.x;
  int i = blockIdx.x * 1024 + t;
  unsigned v = (i < NN) ? hist[i] : 0u;
  sc[t] = v;
  __syncthreads();
  for (int o = 1; o < 1024; o <<= 1) {
    unsigned add = (t >= o) ? sc[t - o] : 0u;
    __syncthreads();
    sc[t] += add;
    __syncthreads();
  }
  if (i < NN) rowptr[i] = sc[t] - v;  // exclusive
  if (t == 1023) part[blockIdx.x] = sc[1023];
}
__global__ void k_scan2(unsigned* part) {
  if (threadIdx.x == 0) {
    unsigned run = 0;
    for (int b = 0; b < NB1; b++) { unsigned t = part[b]; part[b] = run; run += t; }
  }
}
__global__ void k_scan3(unsigned* rowptr, const unsigned* part, unsigned* cursor) {
  int i = blockIdx.x * blockDim.x + threadIdx.x;
  if (i < NN) {
    unsigned r = rowptr[i] + part[i >> 10];
    rowptr[i] = r;
    cursor[i] = r;
  }
  if (i == 0) rowptr[NN] = EE;
}
__global__ void k_scatter(const int* dst, unsigned* cursor, int* eidx) {
  int e = blockIdx.x * blockDim.x + threadIdx.x;
  if (e >= EE) return;
  unsigned pos = atomicAdd(&cursor[dst[e]], 1u);
  eidx[pos] = e;
}

// ---------- K3: MFMA xw1(bf16) = x(bf16)@W1 [N,256] ----------
// A: x [NN,128] bf16 row-major. B: W1t [256,128] bf16 (N-major). 4 waves x 32 rows.
__global__ __launch_bounds__(256) void k_gemm1(const unsigned short* x,
                                               const unsigned short* W1t,
                                               unsigned short* xw1) {
  __shared__ char wlds[65536];
  int tid = threadIdx.x;
#pragma unroll
  for (int it = 0; it < 16; it++) {
    int cch = it * 256 + tid;
    int row = cch >> 4, seg = cch & 15;
    uint4 v = *(const uint4*)(W1t + row * 128 + seg * 8);
    *(uint4*)(&wlds[(row * 256 + seg * 16) ^ ((row & 7) << 4)]) = v;
  }
  __syncthreads();
  int wid = tid >> 6, l = tid & 63;
  int cl = l & 15, kh = l >> 4;
  int swz = (cl & 7) << 4;
  long r0 = (long)blockIdx.x * 128 + wid * 32;
  f32x4 acc[2][16];
#pragma unroll
  for (int rt = 0; rt < 2; rt++)
#pragma unroll
    for (int nt = 0; nt < 16; nt++) acc[rt][nt] = {0.f, 0.f, 0.f, 0.f};
  long ra0 = r0 + cl; if (ra0 > NN - 1) ra0 = NN - 1;
  long ra1 = r0 + 16 + cl; if (ra1 > NN - 1) ra1 = NN - 1;
#pragma unroll
  for (int kk = 0; kk < 4; kk++) {
    bf16x8 a0 = *(const bf16x8*)(x + ra0 * 128 + kk * 32 + kh * 8);
    bf16x8 a1 = *(const bf16x8*)(x + ra1 * 128 + kk * 32 + kh * 8);
#pragma unroll
    for (int nt = 0; nt < 16; nt++) {
      bf16x8 b = *(const bf16x8*)(&wlds[(((nt * 16 + cl) * 256) + kk * 64 + kh * 16) ^ swz]);
      acc[0][nt] = __builtin_amdgcn_mfma_f32_16x16x32_bf16(a0, b, acc[0][nt], 0, 0, 0);
      acc[1][nt] = __builtin_amdgcn_mfma_f32_16x16x32_bf16(a1, b, acc[1][nt], 0, 0, 0);
    }
  }
#pragma unroll
  for (int rt = 0; rt < 2; rt++)
#pragma unroll
    for (int nt = 0; nt < 16; nt++)
#pragma unroll
      for (int j = 0; j < 4; j++) {
        long row = r0 + rt * 16 + kh * 4 + j;
        if (row < NN) xw1[row * 256 + nt * 16 + cl] = f2bf(acc[rt][nt][j]);
      }
}

// ---------- K5: MFMA xw2(f32) = h(bf16)@W2 [N,128] ----------
__global__ __launch_bounds__(256) void k_gemm2(const unsigned short* h,
                                               const unsigned short* W2t, float* xw2) {
  __shared__ char wlds[65536];
  int tid = threadIdx.x;
#pragma unroll
  for (int it = 0; it < 16; it++) {
    int cch = it * 256 + tid;
    int row = cch >> 5, seg = cch & 31;
    uint4 v = *(const uint4*)(W2t + row * 256 + seg * 8);
    *(uint4*)(&wlds[(row * 512 + seg * 16) ^ ((row & 7) << 4)]) = v;
  }
  __syncthreads();
  int wid = tid >> 6, l = tid & 63;
  int cl = l & 15, kh = l >> 4;
  int swz = (cl & 7) << 4;
  long r0 = (long)blockIdx.x * 128 + wid * 32;
  f32x4 acc[2][8];
#pragma unroll
  for (int rt = 0; rt < 2; rt++)
#pragma unroll
    for (int nt = 0; nt < 8; nt++) acc[rt][nt] = {0.f, 0.f, 0.f, 0.f};
  long ra0 = r0 + cl; if (ra0 > NN - 1) ra0 = NN - 1;
  long ra1 = r0 + 16 + cl; if (ra1 > NN - 1) ra1 = NN - 1;
#pragma unroll
  for (int kk = 0; kk < 8; kk++) {
    bf16x8 a0 = *(const bf16x8*)(h + ra0 * 256 + kk * 32 + kh * 8);
    bf16x8 a1 = *(const bf16x8*)(h + ra1 * 256 + kk * 32 + kh * 8);
#pragma unroll
    for (int nt = 0; nt < 8; nt++) {
      bf16x8 b = *(const bf16x8*)(&wlds[(((nt * 16 + cl) * 512) + kk * 64 + kh * 16) ^ swz]);
      acc[0][nt] = __builtin_amdgcn_mfma_f32_16x16x32_bf16(a0, b, acc[0][nt], 0, 0, 0);
      acc[1][nt] = __builtin_amdgcn_mfma_f32_16x16x32_bf16(a1, b, acc[1][nt], 0, 0, 0);
    }
  }
#pragma unroll
  for (int rt = 0; rt < 2; rt++)
#pragma unroll
    for (int nt = 0; nt < 8; nt++)
#pragma unroll
      for (int j = 0; j < 4; j++) {
        long row = r0 + rt * 16 + kh * 4 + j;
        if (row < NN) xw2[row * 128 + nt * 16 + cl] = acc[rt][nt][j];
      }
}

// ---------- K4: layer-1 GAT, wave per dst node, online softmax ----------
__global__ __launch_bounds__(256) void k_gat1(
    const unsigned* rowptr, const int* eidx, const int* srcv, const float* ea_g,
    const float* al_s1, const float* al_d1, const float* V1,
    const unsigned short* xw1, const float* b1, const float* us2, const float* ud2,
    unsigned short* h, float* al_s2, float* al_d2, float* lattr) {
  int w = threadIdx.x >> 6, lane = threadIdx.x & 63;
  int i = blockIdx.x * 4 + w;
  if (i >= NN) return;
  int r0 = rowptr[i], r1 = rowptr[i + 1];
  float v1k[5];
  float ald = 0.f, als_self = 0.f;
  if (lane < 8) {
#pragma unroll
    for (int k = 0; k < 5; k++) v1k[k] = V1[k * 8 + lane];
    ald = al_d1[i * 8 + lane];
    als_self = al_s1[i * 8 + lane];
  }
  int head = lane >> 3;
  float m = -1e30f, l = 0.f;
  float a0 = 0.f, a1 = 0.f, a2 = 0.f, a3 = 0.f;
  float sea = 0.f;  // lanes 0..4 accumulate ea sum
  for (int j = r0; j < r1; j++) {
    int e = eidx[j];
    int s = srcv[e];
    float al = 0.f;
    if (lane < 8) {
      float ale = 0.f;
#pragma unroll
      for (int k = 0; k < 5; k++) ale = fmaf(ea_g[(size_t)e * 5 + k], v1k[k], ale);
      al = al_s1[s * 8 + lane] + ald + ale;
      al = al > 0.f ? al : 0.2f * al;
    }
    if (lane < 5) sea += ea_g[(size_t)e * 5 + lane];
    float myal = __shfl(al, head);
    float mn = fmaxf(m, myal);
    float scale = __expf(m - mn);
    float p = __expf(myal - mn);
    m = mn;
    l = l * scale + p;
    ushort4 xv = ((const ushort4*)(xw1 + (size_t)s * 256))[lane];
    a0 = fmaf(p, bf2f(xv.x), a0 * scale);
    a1 = fmaf(p, bf2f(xv.y), a1 * scale);
    a2 = fmaf(p, bf2f(xv.z), a2 * scale);
    a3 = fmaf(p, bf2f(xv.w), a3 * scale);
  }
  // self-loop: edge_attr = mean of incoming (0 if none)
  float inv = 1.f / fmaxf((float)(r1 - r0), 1.f);
  float la0 = __shfl(sea, 0) * inv, la1 = __shfl(sea, 1) * inv, la2 = __shfl(sea, 2) * inv,
        la3 = __shfl(sea, 3) * inv, la4 = __shfl(sea, 4) * inv;
  if (lane < 5) lattr[i * 5 + lane] = sea * inv;
  float al = 0.f;
  if (lane < 8) {
    float ale = fmaf(la0, v1k[0], fmaf(la1, v1k[1], fmaf(la2, v1k[2],
                fmaf(la3, v1k[3], la4 * v1k[4]))));
    al = als_self + ald + ale;
    al = al > 0.f ? al : 0.2f * al;
  }
  float myal = __shfl(al, head);
  float mn = fmaxf(m, myal);
  float scale = __expf(m - mn);
  float p = __expf(myal - mn);
  l = l * scale + p;
  ushort4 xv = ((const ushort4*)(xw1 + (size_t)i * 256))[lane];
  a0 = fmaf(p, bf2f(xv.x), a0 * scale);
  a1 = fmaf(p, bf2f(xv.y), a1 * scale);
  a2 = fmaf(p, bf2f(xv.z), a2 * scale);
  a3 = fmaf(p, bf2f(xv.w), a3 * scale);
  // finalize: /l + b1, elu
  float invl = 1.f / (l + 1e-16f);
  float4 bv = ((const float4*)b1)[lane];
  float v0 = a0 * invl + bv.x, v1 = a1 * invl + bv.y;
  float v2 = a2 * invl + bv.z, v3 = a3 * invl + bv.w;
  v0 = v0 > 0.f ? v0 : expm1f(v0);
  v1 = v1 > 0.f ? v1 : expm1f(v1);
  v2 = v2 > 0.f ? v2 : expm1f(v2);
  v3 = v3 > 0.f ? v3 : expm1f(v3);
  ushort4 hv;
  hv.x = f2bf(v0); hv.y = f2bf(v1); hv.z = f2bf(v2); hv.w = f2bf(v3);
  ((ushort4*)(h + (size_t)i * 256))[lane] = hv;
  // layer-2 logit pieces
  float4 uv = ((const float4*)us2)[lane];
  float4 dv = ((const float4*)ud2)[lane];
  float ps = v0 * uv.x + v1 * uv.y + v2 * uv.z + v3 * uv.w;
  float pd = v0 * dv.x + v1 * dv.y + v2 * dv.z + v3 * dv.w;
  ps = wave_sum(ps);
  pd = wave_sum(pd);
  if (lane == 0) { al_s2[i] = ps; al_d2[i] = pd; }
}

// ---------- K6: layer-2 GAT, wave per dst node, online softmax ----------
__global__ __launch_bounds__(256) void k_gat2(
    const unsigned* rowptr, const int* eidx, const int* srcv, const float* ea_g,
    const float* al_s2, const float* al_d2, const float* V2, const float* lattr,
    const float* xw2, const float* b2, float* out) {
  int w = threadIdx.x >> 6, lane = threadIdx.x & 63;
  int i = blockIdx.x * 4 + w;
  if (i >= NN) return;
  int r0 = rowptr[i], r1 = rowptr[i + 1];
  float v2k[5];
#pragma unroll
  for (int k = 0; k < 5; k++) v2k[k] = V2[k];
  float ald = al_d2[i];
  float m = -1e30f, l = 0.f, a0 = 0.f, a1 = 0.f;
  for (int j = r0; j < r1; j++) {
    int e = eidx[j];
    int s = srcv[e];
    float ale = 0.f;
#pragma unroll
    for (int k = 0; k < 5; k++) ale = fmaf(ea_g[(size_t)e * 5 + k], v2k[k], ale);
    float al = al_s2[s] + ald + ale;
    al = al > 0.f ? al : 0.2f * al;
    float mn = fmaxf(m, al);
    float scale = __expf(m - mn);
    float p = __expf(al - mn);
    m = mn;
    l = l * scale + p;
    float2 xv = ((const float2*)(xw2 + (size_t)s * 128))[lane];
    a0 = fmaf(p, xv.x, a0 * scale);
    a1 = fmaf(p, xv.y, a1 * scale);
  }
  // self loop
  float ale = 0.f;
#pragma unroll
  for (int k = 0; k < 5; k++) ale = fmaf(lattr[i * 5 + k], v2k[k], ale);
  float al = al_s2[i] + ald + ale;
  al = al > 0.f ? al : 0.2f * al;
  float mn = fmaxf(m, al);
  float scale = __expf(m - mn);
  float p = __expf(al - mn);
  l = l * scale + p;
  float2 xv = ((const float2*)(xw2 + (size_t)i * 128))[lane];
  a0 = fmaf(p, xv.x, a0 * scale);
  a1 = fmaf(p, xv.y, a1 * scale);
  float invl = 1.f / (l + 1e-16f);
  float2 bv = ((const float2*)b2)[lane];
  float2 ov = {a0 * invl + bv.x, a1 * invl + bv.y};
  ((float2*)(out + (size_t)i * 128))[lane] = ov;
}

extern "C" void kernel_launch(void* const* d_in, const int* in_sizes, int n_in,
                              void* d_out, int out_size, void* d_ws, size_t ws_size,
                              hipStream_t stream) {
  const float* pol_feat = (const float*)d_in[0];
  const int* state_ids = (const int*)d_in[1];
  const int* comp_cat = (const int*)d_in[2];
  const float* comp_price = (const float*)d_in[3];
  const int* edge_index = (const int*)d_in[4];
  const float* edge_attr = (const float*)d_in[5];
  const float* Wp = (const float*)d_in[6];
  const float* bp = (const float*)d_in[7];
  const float* state_emb = (const float*)d_in[8];
  const float* sector_emb = (const float*)d_in[9];
  const float* industry_emb = (const float*)d_in[10];
  const float* Wc = (const float*)d_in[11];
  const float* bc = (const float*)d_in[12];
  const float* ln_g = (const float*)d_in[13];
  const float* ln_b = (const float*)d_in[14];
  const float* W1 = (const float*)d_in[15];
  const float* as1 = (const float*)d_in[16];
  const float* ad1 = (const float*)d_in[17];
  const float* We1 = (const float*)d_in[18];
  const float* ae1 = (const float*)d_in[19];
  const float* b1 = (const float*)d_in[20];
  const float* W2 = (const float*)d_in[21];
  const float* as2 = (const float*)d_in[22];
  const float* ad2 = (const float*)d_in[23];
  const float* We2 = (const float*)d_in[24];
  const float* ae2 = (const float*)d_in[25];
  const float* b2 = (const float*)d_in[26];
  const int* srcv = edge_index;
  const int* dstv = edge_index + EE;
  float* out = (float*)d_out;

  // ---- workspace layout (aliased; peak ~120 MiB) ----
  size_t off = 0;
  auto alloc = [&](size_t nbytes) -> char* {
    char* p = (char*)d_ws + off;
    off += ((nbytes + 255) & ~(size_t)255);
    return p;
  };
  // region A: xw1 (bf16, NN*256*2) == xw2 (f32, NN*128*4) — same byte size
  char* regA = alloc((size_t)NN * 512);
  // region B: h (bf16, NN*256*2); x (bf16, NN*128*2) occupies first half (dead after gemm1)
  char* regB = alloc((size_t)NN * 512);
  unsigned short* xw1 = (unsigned short*)regA;
  float* xw2 = (float*)regA;
  unsigned short* h = (unsigned short*)regB;
  unsigned short* x = (unsigned short*)regB;
  float* al_s1 = (float*)alloc((size_t)NN * 8 * 4);
  float* al_d1 = (float*)alloc((size_t)NN * 8 * 4);
  float* al_s2 = (float*)alloc((size_t)NN * 4);
  float* al_d2 = (float*)alloc((size_t)NN * 4);
  float* lattr = (float*)alloc((size_t)NN * 5 * 4);
  float* us2 = (float*)alloc(256 * 4);
  float* ud2 = (float*)alloc(256 * 4);
  float* V1 = (float*)alloc(64 * 4);
  float* V2 = (float*)alloc(8 * 4);
  float* ws1h = (float*)alloc(128 * 8 * 4);
  float* wd1h = (float*)alloc(128 * 8 * 4);
  unsigned short* W1t = (unsigned short*)alloc(32768 * 2);
  unsigned short* W2t = (unsigned short*)alloc(32768 * 2);
  unsigned* hist = (unsigned*)alloc((size_t)NN * 4);
  unsigned* rowptr = (unsigned*)alloc((size_t)(NN + 1) * 4);
  unsigned* cursor = (unsigned*)alloc((size_t)NN * 4);
  unsigned* part = (unsigned*)alloc((size_t)NB1 * 4);
  int* eidx = (int*)alloc((size_t)EE * 4);

  hipMemsetAsync(hist, 0, (size_t)NN * 4, stream);

  k_pre<<<1, 256, 0, stream>>>(W2, as2, ad2, We1, ae1, We2, ae2, W1, as1, ad1, us2,
                               ud2, V1, V2, ws1h, wd1h);
  k_prew<<<256, 256, 0, stream>>>(W1, W2, W1t, W2t);
  k_encode<<<NN, 128, 0, stream>>>(pol_feat, state_ids, comp_cat, comp_price, Wp, bp,
                                   state_emb, sector_emb, industry_emb, Wc, bc, ln_g,
                                   ln_b, ws1h, wd1h, x, al_s1, al_d1);
  k_hist<<<(EE + 255) / 256, 256, 0, stream>>>(dstv, hist);
  k_scan1<<<NB1, 1024, 0, stream>>>(hist, rowptr, part);
  k_scan2<<<1, 64, 0, stream>>>(part);
  k_scan3<<<(NN + 255) / 256, 256, 0, stream>>>(rowptr, part, cursor);
  k_scatter<<<(EE + 255) / 256, 256, 0, stream>>>(dstv, cursor, eidx);
  k_gemm1<<<(NN + 127) / 128, 256, 0, stream>>>(x, W1t, xw1);
  k_gat1<<<NN / 4, 256, 0, stream>>>(rowptr, eidx, srcv, edge_attr, al_s1, al_d1, V1,
                                     xw1, b1, us2, ud2, h, al_s2, al_d2, lattr);
  k_gemm2<<<(NN + 127) / 128, 256, 0, stream>>>(h, W2t, xw2);
  k_gat2<<<NN / 4, 256, 0, stream>>>(rowptr, eidx, srcv, edge_attr, al_s2, al_d2, V2,
                                     lattr, xw2, b2, out);
}

// Round 5
// 582.364 us; speedup vs baseline: 10.4946x; 1.3671x over previous
//
#include <hip/hip_runtime.h>
#include <math.h>

#define N_POL 20000
#define N_COMP 80000
#define NN (N_POL + N_COMP)
#define EE 1000000
#define NB1 ((NN + 1023) / 1024)  // scan blocks

typedef short bf16x8 __attribute__((ext_vector_type(8)));
typedef float f32x4 __attribute__((ext_vector_type(4)));

// ---------- helpers ----------
__device__ __forceinline__ float wave_sum(float v) {
#pragma unroll
  for (int o = 32; o > 0; o >>= 1) v += __shfl_xor(v, o);
  return v;
}
__device__ __forceinline__ float wave_max(float v) {
#pragma unroll
  for (int o = 32; o > 0; o >>= 1) v = fmaxf(v, __shfl_xor(v, o));
  return v;
}
__device__ __forceinline__ unsigned short f2bf(float f) {
  unsigned b = __float_as_uint(f);
  return (unsigned short)((b + 0x7FFFu + ((b >> 16) & 1u)) >> 16);
}
__device__ __forceinline__ float bf2f(unsigned short u) {
  return __uint_as_float(((unsigned)u) << 16);
}

// ---------- K0: tiny precomputes ----------
__global__ void k_pre(const float* W2, const float* as2, const float* ad2,
                      const float* We1, const float* ae1, const float* We2,
                      const float* ae2, const float* W1, const float* as1,
                      const float* ad1, float* us2, float* ud2, float* V1, float* V2,
                      float* ws1h, float* wd1h) {
  int t = threadIdx.x;
  if (t < 256) {
    float s = 0.f, d = 0.f;
    for (int c = 0; c < 128; c++) {
      float w = W2[t * 128 + c];
      s = fmaf(w, as2[c], s);
      d = fmaf(w, ad2[c], d);
    }
    us2[t] = s; ud2[t] = d;
  }
  if (t < 128) {
    for (int h = 0; h < 8; h++) {
      float s = 0.f, d = 0.f;
      for (int c = 0; c < 32; c++) {
        float w = W1[t * 256 + h * 32 + c];
        s = fmaf(w, as1[h * 32 + c], s);
        d = fmaf(w, ad1[h * 32 + c], d);
      }
      ws1h[t * 8 + h] = s;
      wd1h[t * 8 + h] = d;
    }
  }
  if (t < 40) {
    int k = t >> 3, h = t & 7;
    float v = 0.f;
    for (int c = 0; c < 32; c++) v = fmaf(We1[k * 256 + h * 32 + c], ae1[h * 32 + c], v);
    V1[k * 8 + h] = v;
  }
  if (t < 5) {
    float v = 0.f;
    for (int c = 0; c < 128; c++) v = fmaf(We2[t * 128 + c], ae2[c], v);
    V2[t] = v;
  }
}

// ---------- weight transposes to [N][K] bf16 ----------
__global__ void k_prew(const float* W1, const float* W2, unsigned short* W1t,
                       unsigned short* W2t) {
  int id = blockIdx.x * 256 + threadIdx.x;
  if (id < 32768) {
    int n = id >> 7, k = id & 127;
    W1t[id] = f2bf(W1[k * 256 + n]);
  } else {
    int id2 = id - 32768;
    int n = id2 >> 8, k = id2 & 255;
    W2t[id2] = f2bf(W2[k * 128 + n]);
  }
}

// ---------- K1: node encoders + LayerNorm + layer-1 logit pieces ----------
__global__ __launch_bounds__(128) void k_encode(
    const float* pol_feat, const int* state_ids, const int* comp_cat,
    const float* comp_price, const float* Wp, const float* bp,
    const float* state_emb, const float* sector_emb, const float* industry_emb,
    const float* Wc, const float* bc, const float* ln_g, const float* ln_b,
    const float* ws1h, const float* wd1h, unsigned short* x, float* al_s1,
    float* al_d1) {
  int i = blockIdx.x, c = threadIdx.x;
  float v;
  if (i < N_POL) {
    float acc = bp[c];
#pragma unroll
    for (int k = 0; k < 7; k++) acc = fmaf(pol_feat[i * 7 + k], Wp[k * 128 + c], acc);
    v = fmaxf(acc, 0.f) + state_emb[state_ids[i] * 128 + c];
  } else {
    int j = i - N_POL;
    int sc = comp_cat[2 * j], in = comp_cat[2 * j + 1];
    float acc = bc[c];
#pragma unroll
    for (int k = 0; k < 8; k++) acc = fmaf(sector_emb[sc * 8 + k], Wc[k * 128 + c], acc);
#pragma unroll
    for (int k = 0; k < 8; k++) acc = fmaf(industry_emb[in * 8 + k], Wc[(8 + k) * 128 + c], acc);
    acc = fmaf(comp_price[j], Wc[16 * 128 + c], acc);
    v = fmaxf(acc, 0.f);
  }
  __shared__ float red[2];
  __shared__ float xs[128];
  int wid = c >> 6, lane = c & 63;
  float s = wave_sum(v);
  if (lane == 0) red[wid] = s;
  __syncthreads();
  float mu = (red[0] + red[1]) * (1.f / 128.f);
  float t0 = v - mu;
  __syncthreads();
  float s2 = wave_sum(t0 * t0);
  if (lane == 0) red[wid] = s2;
  __syncthreads();
  float var = (red[0] + red[1]) * (1.f / 128.f);
  float r = rsqrtf(var + 1e-5f);
  float xf = t0 * r * ln_g[c] + ln_b[c];
  x[(size_t)i * 128 + c] = f2bf(xf);
  xs[c] = xf;
  __syncthreads();
  if (c < 16) {
    int hh = c & 7;
    const float* wv = (c < 8) ? ws1h : wd1h;
    float dot = 0.f;
    for (int k2 = 0; k2 < 128; k2++) dot = fmaf(xs[k2], wv[k2 * 8 + hh], dot);
    if (c < 8) al_s1[i * 8 + hh] = dot;
    else al_d1[i * 8 + hh] = dot;
  }
}

// ---------- CSR build ----------
__global__ void k_hist(const int* dst, unsigned* hist) {
  int e = blockIdx.x * blockDim.x + threadIdx.x;
  if (e < EE) atomicAdd(&hist[dst[e]], 1u);
}
__global__ __launch_bounds__(1024) void k_scan1(const unsigned* hist, unsigned* rowptr,
                                                unsigned* part) {
  __shared__ unsigned sc[1024];
  int t = threadIdx.x;
  int i = blockIdx.x * 1024 + t;
  unsigned v = (i < NN) ? hist[i] : 0u;
  sc[t] = v;
  __syncthreads();
  for (int o = 1; o < 1024; o <<= 1) {
    unsigned add = (t >= o) ? sc[t - o] : 0u;
    __syncthreads();
    sc[t] += add;
    __syncthreads();
  }
  if (i < NN) rowptr[i] = sc[t] - v;  // exclusive
  if (t == 1023) part[blockIdx.x] = sc[1023];
}
__global__ void k_scan2(unsigned* part) {
  if (threadIdx.x == 0) {
    unsigned run = 0;
    for (int b = 0; b < NB1; b++) { unsigned t = part[b]; part[b] = run; run += t; }
  }
}
__global__ void k_scan3(unsigned* rowptr, const unsigned* part, unsigned* cursor) {
  int i = blockIdx.x * blockDim.x + threadIdx.x;
  if (i < NN) {
    unsigned r = rowptr[i] + part[i >> 10];
    rowptr[i] = r;
    cursor[i] = r;
  }
  if (i == 0) rowptr[NN] = EE;
}
// scatter: permuted src ids + precomputed edge-attention pieces
__global__ void k_scatter(const int* src, const int* dst, const float* ea,
                          const float* V1, const float* V2, unsigned* cursor,
                          int* esrc, float* ale1, float* ale2) {
  int e = blockIdx.x * blockDim.x + threadIdx.x;
  if (e >= EE) return;
  int d = dst[e];
  unsigned pos = atomicAdd(&cursor[d], 1u);
  esrc[pos] = src[e];
  float av[5];
#pragma unroll
  for (int k = 0; k < 5; k++) av[k] = ea[(size_t)e * 5 + k];
  float a2 = 0.f;
#pragma unroll
  for (int k = 0; k < 5; k++) a2 = fmaf(av[k], V2[k], a2);
  ale2[pos] = a2;
#pragma unroll
  for (int hh = 0; hh < 8; hh++) {
    float a1 = 0.f;
#pragma unroll
    for (int k = 0; k < 5; k++) a1 = fmaf(av[k], V1[k * 8 + hh], a1);
    ale1[(size_t)pos * 8 + hh] = a1;
  }
}

// ---------- K3: MFMA xw1(bf16) = x(bf16)@W1 [N,256] ----------
__global__ __launch_bounds__(256) void k_gemm1(const unsigned short* x,
                                               const unsigned short* W1t,
                                               unsigned short* xw1) {
  __shared__ char wlds[65536];
  int tid = threadIdx.x;
#pragma unroll
  for (int it = 0; it < 16; it++) {
    int cch = it * 256 + tid;
    int row = cch >> 4, seg = cch & 15;
    uint4 v = *(const uint4*)(W1t + row * 128 + seg * 8);
    *(uint4*)(&wlds[(row * 256 + seg * 16) ^ ((row & 7) << 4)]) = v;
  }
  __syncthreads();
  int wid = tid >> 6, l = tid & 63;
  int cl = l & 15, kh = l >> 4;
  int swz = (cl & 7) << 4;
  long r0 = (long)blockIdx.x * 128 + wid * 32;
  f32x4 acc[2][16];
#pragma unroll
  for (int rt = 0; rt < 2; rt++)
#pragma unroll
    for (int nt = 0; nt < 16; nt++) acc[rt][nt] = {0.f, 0.f, 0.f, 0.f};
  long ra0 = r0 + cl; if (ra0 > NN - 1) ra0 = NN - 1;
  long ra1 = r0 + 16 + cl; if (ra1 > NN - 1) ra1 = NN - 1;
#pragma unroll
  for (int kk = 0; kk < 4; kk++) {
    bf16x8 a0 = *(const bf16x8*)(x + ra0 * 128 + kk * 32 + kh * 8);
    bf16x8 a1 = *(const bf16x8*)(x + ra1 * 128 + kk * 32 + kh * 8);
#pragma unroll
    for (int nt = 0; nt < 16; nt++) {
      bf16x8 b = *(const bf16x8*)(&wlds[(((nt * 16 + cl) * 256) + kk * 64 + kh * 16) ^ swz]);
      acc[0][nt] = __builtin_amdgcn_mfma_f32_16x16x32_bf16(a0, b, acc[0][nt], 0, 0, 0);
      acc[1][nt] = __builtin_amdgcn_mfma_f32_16x16x32_bf16(a1, b, acc[1][nt], 0, 0, 0);
    }
  }
#pragma unroll
  for (int rt = 0; rt < 2; rt++)
#pragma unroll
    for (int nt = 0; nt < 16; nt++)
#pragma unroll
      for (int j = 0; j < 4; j++) {
        long row = r0 + rt * 16 + kh * 4 + j;
        if (row < NN) xw1[row * 256 + nt * 16 + cl] = f2bf(acc[rt][nt][j]);
      }
}

// ---------- K5: MFMA xw2(bf16) = h(bf16)@W2 [N,128] ----------
__global__ __launch_bounds__(256) void k_gemm2(const unsigned short* h,
                                               const unsigned short* W2t,
                                               unsigned short* xw2) {
  __shared__ char wlds[65536];
  int tid = threadIdx.x;
#pragma unroll
  for (int it = 0; it < 16; it++) {
    int cch = it * 256 + tid;
    int row = cch >> 5, seg = cch & 31;
    uint4 v = *(const uint4*)(W2t + row * 256 + seg * 8);
    *(uint4*)(&wlds[(row * 512 + seg * 16) ^ ((row & 7) << 4)]) = v;
  }
  __syncthreads();
  int wid = tid >> 6, l = tid & 63;
  int cl = l & 15, kh = l >> 4;
  int swz = (cl & 7) << 4;
  long r0 = (long)blockIdx.x * 128 + wid * 32;
  f32x4 acc[2][8];
#pragma unroll
  for (int rt = 0; rt < 2; rt++)
#pragma unroll
    for (int nt = 0; nt < 8; nt++) acc[rt][nt] = {0.f, 0.f, 0.f, 0.f};
  long ra0 = r0 + cl; if (ra0 > NN - 1) ra0 = NN - 1;
  long ra1 = r0 + 16 + cl; if (ra1 > NN - 1) ra1 = NN - 1;
#pragma unroll
  for (int kk = 0; kk < 8; kk++) {
    bf16x8 a0 = *(const bf16x8*)(h + ra0 * 256 + kk * 32 + kh * 8);
    bf16x8 a1 = *(const bf16x8*)(h + ra1 * 256 + kk * 32 + kh * 8);
#pragma unroll
    for (int nt = 0; nt < 8; nt++) {
      bf16x8 b = *(const bf16x8*)(&wlds[(((nt * 16 + cl) * 512) + kk * 64 + kh * 16) ^ swz]);
      acc[0][nt] = __builtin_amdgcn_mfma_f32_16x16x32_bf16(a0, b, acc[0][nt], 0, 0, 0);
      acc[1][nt] = __builtin_amdgcn_mfma_f32_16x16x32_bf16(a1, b, acc[1][nt], 0, 0, 0);
    }
  }
#pragma unroll
  for (int rt = 0; rt < 2; rt++)
#pragma unroll
    for (int nt = 0; nt < 8; nt++)
#pragma unroll
      for (int j = 0; j < 4; j++) {
        long row = r0 + rt * 16 + kh * 4 + j;
        if (row < NN) xw2[row * 128 + nt * 16 + cl] = f2bf(acc[rt][nt][j]);
      }
}

// ---------- K4: layer-1 GAT, wave per dst node, chunked two-phase softmax ----------
// Pass A: 8 edges x 8 heads across 64 lanes; pass B: pipelined gather+fma.
__global__ __launch_bounds__(256) void k_gat1(
    const unsigned* rowptr, const int* esrc, const float* ale1e, const float* al_s1,
    const float* al_d1, const unsigned short* xw1, const float* b1, const float* us2,
    const float* ud2, unsigned short* h, float* al_s2, float* al_d2) {
  int w = threadIdx.x >> 6, lane = threadIdx.x & 63;
  int i = blockIdx.x * 4 + w;
  if (i >= NN) return;
  int r0 = rowptr[i], r1 = rowptr[i + 1];
  int hh = lane & 7;   // head (pass A)
  int js = lane >> 3;  // edge-sub (pass A)
  int ah = lane >> 3;  // head owning channels lane*4..lane*4+3 (pass B)
  float ald = al_d1[i * 8 + hh];
  float m = -1e30f, l = 0.f;
  float a0 = 0.f, a1 = 0.f, a2 = 0.f, a3 = 0.f;
  float alesum = 0.f;

  auto chunk = [&](int jb, int cnt) {
    bool valid = js < cnt;
    int jc = jb + (valid ? js : cnt - 1);
    int s = esrc[jc];
    float ale = ale1e[(size_t)jc * 8 + hh];
    if (!valid) ale = 0.f;
    alesum += ale;
    float logit = -1e30f;
    if (valid) {
      float al = al_s1[s * 8 + hh] + ald + ale;
      logit = al > 0.f ? al : 0.2f * al;
    }
    float cm = logit;
    cm = fmaxf(cm, __shfl_xor(cm, 8));
    cm = fmaxf(cm, __shfl_xor(cm, 16));
    cm = fmaxf(cm, __shfl_xor(cm, 32));
    float mn = fmaxf(m, cm);
    float sc = __expf(m - mn);
    float p = __expf(logit - mn);
    float ps = p;
    ps += __shfl_xor(ps, 8);
    ps += __shfl_xor(ps, 16);
    ps += __shfl_xor(ps, 32);
    l = l * sc + ps;
    m = mn;
    float asc = __shfl(sc, ah);
    a0 *= asc; a1 *= asc; a2 *= asc; a3 *= asc;
    for (int jj = 0; jj < cnt; jj++) {
      float pj = __shfl(p, jj * 8 + ah);
      int sj = __shfl(s, jj * 8);
      ushort4 xv = ((const ushort4*)(xw1 + (size_t)sj * 256))[lane];
      a0 = fmaf(pj, bf2f(xv.x), a0);
      a1 = fmaf(pj, bf2f(xv.y), a1);
      a2 = fmaf(pj, bf2f(xv.z), a2);
      a3 = fmaf(pj, bf2f(xv.w), a3);
    }
  };
  int jb = r0;
  for (; jb + 8 <= r1; jb += 8) chunk(jb, 8);
  if (jb < r1) chunk(jb, r1 - jb);

  // self-loop (edge_attr = mean of incoming per-edge ale, by linearity)
  alesum += __shfl_xor(alesum, 8);
  alesum += __shfl_xor(alesum, 16);
  alesum += __shfl_xor(alesum, 32);
  float inv = 1.f / fmaxf((float)(r1 - r0), 1.f);
  float aleS = alesum * inv;
  {
    float al = al_s1[i * 8 + hh] + ald + aleS;
    float logit = al > 0.f ? al : 0.2f * al;
    float mn = fmaxf(m, logit);
    float sc = __expf(m - mn);
    float p = __expf(logit - mn);
    l = l * sc + p;
    m = mn;
    float asc = __shfl(sc, ah);
    float pj = __shfl(p, ah);
    ushort4 xv = ((const ushort4*)(xw1 + (size_t)i * 256))[lane];
    a0 = fmaf(pj, bf2f(xv.x), a0 * asc);
    a1 = fmaf(pj, bf2f(xv.y), a1 * asc);
    a2 = fmaf(pj, bf2f(xv.z), a2 * asc);
    a3 = fmaf(pj, bf2f(xv.w), a3 * asc);
  }
  // finalize: /l + b1, elu
  float lh = __shfl(l, ah);
  float invl = 1.f / (lh + 1e-16f);
  float4 bv = ((const float4*)b1)[lane];
  float v0 = a0 * invl + bv.x, v1 = a1 * invl + bv.y;
  float v2 = a2 * invl + bv.z, v3 = a3 * invl + bv.w;
  v0 = v0 > 0.f ? v0 : expm1f(v0);
  v1 = v1 > 0.f ? v1 : expm1f(v1);
  v2 = v2 > 0.f ? v2 : expm1f(v2);
  v3 = v3 > 0.f ? v3 : expm1f(v3);
  ushort4 hv;
  hv.x = f2bf(v0); hv.y = f2bf(v1); hv.z = f2bf(v2); hv.w = f2bf(v3);
  ((ushort4*)(h + (size_t)i * 256))[lane] = hv;
  // layer-2 logit pieces
  float4 uv = ((const float4*)us2)[lane];
  float4 dv = ((const float4*)ud2)[lane];
  float ps2 = v0 * uv.x + v1 * uv.y + v2 * uv.z + v3 * uv.w;
  float pd2 = v0 * dv.x + v1 * dv.y + v2 * dv.z + v3 * dv.w;
  ps2 = wave_sum(ps2);
  pd2 = wave_sum(pd2);
  if (lane == 0) { al_s2[i] = ps2; al_d2[i] = pd2; }
}

// ---------- K6: layer-2 GAT, wave per dst node, chunked two-phase softmax ----------
__global__ __launch_bounds__(256) void k_gat2(
    const unsigned* rowptr, const int* esrc, const float* ale2e, const float* al_s2,
    const float* al_d2, const unsigned short* xw2, const float* b2, float* out) {
  int w = threadIdx.x >> 6, lane = threadIdx.x & 63;
  int i = blockIdx.x * 4 + w;
  if (i >= NN) return;
  int r0 = rowptr[i], r1 = rowptr[i + 1];
  float ald = al_d2[i];
  float m = -1e30f, l = 0.f, a0 = 0.f, a1 = 0.f;
  float alesum = 0.f;

  auto chunk = [&](int jb, int cnt) {
    bool valid = lane < cnt;
    int jc = jb + (valid ? lane : cnt - 1);
    int s = esrc[jc];
    float ale = valid ? ale2e[jc] : 0.f;
    alesum += ale;
    float logit = -1e30f;
    if (valid) {
      float al = al_s2[s] + ald + ale;
      logit = al > 0.f ? al : 0.2f * al;
    }
    float cm = wave_max(logit);
    float mn = fmaxf(m, cm);
    float sc = __expf(m - mn);
    float p = __expf(logit - mn);
    float ps = wave_sum(p);
    l = l * sc + ps;
    m = mn;
    a0 *= sc; a1 *= sc;
    for (int jj = 0; jj < cnt; jj++) {
      float pj = __shfl(p, jj);
      int sj = __shfl(s, jj);
      ushort2 xv = ((const ushort2*)(xw2 + (size_t)sj * 128))[lane];
      a0 = fmaf(pj, bf2f(xv.x), a0);
      a1 = fmaf(pj, bf2f(xv.y), a1);
    }
  };
  int jb = r0;
  for (; jb + 64 <= r1; jb += 64) chunk(jb, 64);
  if (jb < r1) chunk(jb, r1 - jb);

  // self-loop
  alesum = wave_sum(alesum);
  float inv = 1.f / fmaxf((float)(r1 - r0), 1.f);
  float aleS = alesum * inv;
  {
    float al = al_s2[i] + ald + aleS;
    float logit = al > 0.f ? al : 0.2f * al;
    float mn = fmaxf(m, logit);
    float sc = __expf(m - mn);
    float p = __expf(logit - mn);
    l = l * sc + p;
    ushort2 xv = ((const ushort2*)(xw2 + (size_t)i * 128))[lane];
    a0 = fmaf(p, bf2f(xv.x), a0 * sc);
    a1 = fmaf(p, bf2f(xv.y), a1 * sc);
  }
  float invl = 1.f / (l + 1e-16f);
  float2 bv = ((const float2*)b2)[lane];
  float2 ov = {a0 * invl + bv.x, a1 * invl + bv.y};
  ((float2*)(out + (size_t)i * 128))[lane] = ov;
}

extern "C" void kernel_launch(void* const* d_in, const int* in_sizes, int n_in,
                              void* d_out, int out_size, void* d_ws, size_t ws_size,
                              hipStream_t stream) {
  const float* pol_feat = (const float*)d_in[0];
  const int* state_ids = (const int*)d_in[1];
  const int* comp_cat = (const int*)d_in[2];
  const float* comp_price = (const float*)d_in[3];
  const int* edge_index = (const int*)d_in[4];
  const float* edge_attr = (const float*)d_in[5];
  const float* Wp = (const float*)d_in[6];
  const float* bp = (const float*)d_in[7];
  const float* state_emb = (const float*)d_in[8];
  const float* sector_emb = (const float*)d_in[9];
  const float* industry_emb = (const float*)d_in[10];
  const float* Wc = (const float*)d_in[11];
  const float* bc = (const float*)d_in[12];
  const float* ln_g = (const float*)d_in[13];
  const float* ln_b = (const float*)d_in[14];
  const float* W1 = (const float*)d_in[15];
  const float* as1 = (const float*)d_in[16];
  const float* ad1 = (const float*)d_in[17];
  const float* We1 = (const float*)d_in[18];
  const float* ae1 = (const float*)d_in[19];
  const float* b1 = (const float*)d_in[20];
  const float* W2 = (const float*)d_in[21];
  const float* as2 = (const float*)d_in[22];
  const float* ad2 = (const float*)d_in[23];
  const float* We2 = (const float*)d_in[24];
  const float* ae2 = (const float*)d_in[25];
  const float* b2 = (const float*)d_in[26];
  const int* srcv = edge_index;
  const int* dstv = edge_index + EE;
  float* out = (float*)d_out;

  // ---- workspace layout (aliased; peak ~152 MiB) ----
  size_t off = 0;
  auto alloc = [&](size_t nbytes) -> char* {
    char* p = (char*)d_ws + off;
    off += ((nbytes + 255) & ~(size_t)255);
    return p;
  };
  // region A: xw1 (bf16, NN*256*2); xw2 (bf16, NN*128*2) reuses it after gat1
  char* regA = alloc((size_t)NN * 512);
  // region B: h (bf16, NN*256*2); x (bf16, NN*128*2) occupies first half (dead after gemm1)
  char* regB = alloc((size_t)NN * 512);
  unsigned short* xw1 = (unsigned short*)regA;
  unsigned short* xw2 = (unsigned short*)regA;
  unsigned short* h = (unsigned short*)regB;
  unsigned short* x = (unsigned short*)regB;
  float* al_s1 = (float*)alloc((size_t)NN * 8 * 4);
  float* al_d1 = (float*)alloc((size_t)NN * 8 * 4);
  float* al_s2 = (float*)alloc((size_t)NN * 4);
  float* al_d2 = (float*)alloc((size_t)NN * 4);
  float* us2 = (float*)alloc(256 * 4);
  float* ud2 = (float*)alloc(256 * 4);
  float* V1 = (float*)alloc(64 * 4);
  float* V2 = (float*)alloc(8 * 4);
  float* ws1h = (float*)alloc(128 * 8 * 4);
  float* wd1h = (float*)alloc(128 * 8 * 4);
  unsigned short* W1t = (unsigned short*)alloc(32768 * 2);
  unsigned short* W2t = (unsigned short*)alloc(32768 * 2);
  unsigned* hist = (unsigned*)alloc((size_t)NN * 4);
  unsigned* rowptr = (unsigned*)alloc((size_t)(NN + 1) * 4);
  unsigned* cursor = (unsigned*)alloc((size_t)NN * 4);
  unsigned* part = (unsigned*)alloc((size_t)NB1 * 4);
  int* esrc = (int*)alloc((size_t)EE * 4);
  float* ale1 = (float*)alloc((size_t)EE * 8 * 4);
  float* ale2 = (float*)alloc((size_t)EE * 4);

  hipMemsetAsync(hist, 0, (size_t)NN * 4, stream);

  k_pre<<<1, 256, 0, stream>>>(W2, as2, ad2, We1, ae1, We2, ae2, W1, as1, ad1, us2,
                               ud2, V1, V2, ws1h, wd1h);
  k_prew<<<256, 256, 0, stream>>>(W1, W2, W1t, W2t);
  k_encode<<<NN, 128, 0, stream>>>(pol_feat, state_ids, comp_cat, comp_price, Wp, bp,
                                   state_emb, sector_emb, industry_emb, Wc, bc, ln_g,
                                   ln_b, ws1h, wd1h, x, al_s1, al_d1);
  k_hist<<<(EE + 255) / 256, 256, 0, stream>>>(dstv, hist);
  k_scan1<<<NB1, 1024, 0, stream>>>(hist, rowptr, part);
  k_scan2<<<1, 64, 0, stream>>>(part);
  k_scan3<<<(NN + 255) / 256, 256, 0, stream>>>(rowptr, part, cursor);
  k_scatter<<<(EE + 255) / 256, 256, 0, stream>>>(srcv, dstv, edge_attr, V1, V2,
                                                  cursor, esrc, ale1, ale2);
  k_gemm1<<<(NN + 127) / 128, 256, 0, stream>>>(x, W1t, xw1);
  k_gat1<<<NN / 4, 256, 0, stream>>>(rowptr, esrc, ale1, al_s1, al_d1, xw1, b1, us2,
                                     ud2, h, al_s2, al_d2);
  k_gemm2<<<(NN + 127) / 128, 256, 0, stream>>>(h, W2t, xw2);
  k_gat2<<<NN / 4, 256, 0, stream>>>(rowptr, esrc, ale2, al_s2, al_d2, xw2, b2, out);
}

// Round 6
// 444.235 us; speedup vs baseline: 13.7577x; 1.3109x over previous
//
#include <hip/hip_runtime.h>
#include <hip/hip_fp16.h>
#include <math.h>

#define N_POL 20000
#define N_COMP 80000
#define NN (N_POL + N_COMP)
#define EE 1000000
#define NB1 ((NN + 1023) / 1024)  // scan blocks

typedef short bf16x8 __attribute__((ext_vector_type(8)));
typedef float f32x4 __attribute__((ext_vector_type(4)));

// 32B interleaved permuted-edge record: 1 cache line touch per scatter
struct __align__(16) PEdge {
  int s;              // src node
  float ale2;         // ea . V2
  unsigned short a1[8];  // fp16 ea . V1[:,h]
  unsigned pad[2];
};

// ---------- helpers ----------
__device__ __forceinline__ float wave_sum(float v) {
#pragma unroll
  for (int o = 32; o > 0; o >>= 1) v += __shfl_xor(v, o);
  return v;
}
__device__ __forceinline__ float wave_max(float v) {
#pragma unroll
  for (int o = 32; o > 0; o >>= 1) v = fmaxf(v, __shfl_xor(v, o));
  return v;
}
__device__ __forceinline__ unsigned short f2bf(float f) {
  unsigned b = __float_as_uint(f);
  return (unsigned short)((b + 0x7FFFu + ((b >> 16) & 1u)) >> 16);
}
__device__ __forceinline__ float bf2f(unsigned short u) {
  return __uint_as_float(((unsigned)u) << 16);
}
__device__ __forceinline__ unsigned short f2h(float f) {
  __half h = __float2half_rn(f);
  return *(unsigned short*)&h;
}
__device__ __forceinline__ float h2f(unsigned short u) {
  __half h = *(__half*)&u;
  return __half2float(h);
}

// ---------- K0: tiny precomputes ----------
__global__ void k_pre(const float* W2, const float* as2, const float* ad2,
                      const float* We1, const float* ae1, const float* We2,
                      const float* ae2, float* us2, float* ud2, float* V1, float* V2) {
  int t = threadIdx.x;
  if (t < 256) {
    float s = 0.f, d = 0.f;
    for (int c = 0; c < 128; c++) {
      float w = W2[t * 128 + c];
      s = fmaf(w, as2[c], s);
      d = fmaf(w, ad2[c], d);
    }
    us2[t] = s; ud2[t] = d;
  }
  if (t < 40) {
    int k = t >> 3, h = t & 7;
    float v = 0.f;
    for (int c = 0; c < 32; c++) v = fmaf(We1[k * 256 + h * 32 + c], ae1[h * 32 + c], v);
    V1[k * 8 + h] = v;
  }
  if (t < 5) {
    float v = 0.f;
    for (int c = 0; c < 128; c++) v = fmaf(We2[t * 128 + c], ae2[c], v);
    V2[t] = v;
  }
}

// ---------- weight transposes to [N][K] bf16 ----------
__global__ void k_prew(const float* W1, const float* W2, unsigned short* W1t,
                       unsigned short* W2t) {
  int id = blockIdx.x * 256 + threadIdx.x;
  if (id < 32768) {
    int n = id >> 7, k = id & 127;
    W1t[id] = f2bf(W1[k * 256 + n]);
  } else {
    int id2 = id - 32768;
    int n = id2 >> 8, k = id2 & 255;
    W2t[id2] = f2bf(W2[k * 128 + n]);
  }
}

// ---------- K1: node encoders + LayerNorm (2 nodes / 256-block) ----------
__global__ __launch_bounds__(256) void k_encode(
    const float* pol_feat, const int* state_ids, const int* comp_cat,
    const float* comp_price, const float* Wp, const float* bp,
    const float* state_emb, const float* sector_emb, const float* industry_emb,
    const float* Wc, const float* bc, const float* ln_g, const float* ln_b,
    unsigned short* x) {
  int t = threadIdx.x;
  int i = blockIdx.x * 2 + (t >> 7), c = t & 127;
  float v;
  if (i < N_POL) {
    float acc = bp[c];
#pragma unroll
    for (int k = 0; k < 7; k++) acc = fmaf(pol_feat[i * 7 + k], Wp[k * 128 + c], acc);
    v = fmaxf(acc, 0.f) + state_emb[state_ids[i] * 128 + c];
  } else {
    int j = i - N_POL;
    int sc = comp_cat[2 * j], in = comp_cat[2 * j + 1];
    float acc = bc[c];
#pragma unroll
    for (int k = 0; k < 8; k++) acc = fmaf(sector_emb[sc * 8 + k], Wc[k * 128 + c], acc);
#pragma unroll
    for (int k = 0; k < 8; k++) acc = fmaf(industry_emb[in * 8 + k], Wc[(8 + k) * 128 + c], acc);
    acc = fmaf(comp_price[j], Wc[16 * 128 + c], acc);
    v = fmaxf(acc, 0.f);
  }
  __shared__ float red[4];
  int wid = t >> 6, lane = t & 63;
  int base = (t >> 7) << 1;
  float s = wave_sum(v);
  if (lane == 0) red[wid] = s;
  __syncthreads();
  float mu = (red[base] + red[base + 1]) * (1.f / 128.f);
  float t0 = v - mu;
  __syncthreads();
  float s2 = wave_sum(t0 * t0);
  if (lane == 0) red[wid] = s2;
  __syncthreads();
  float var = (red[base] + red[base + 1]) * (1.f / 128.f);
  float r = rsqrtf(var + 1e-5f);
  float xf = t0 * r * ln_g[c] + ln_b[c];
  x[(size_t)i * 128 + c] = f2bf(xf);
}

// ---------- CSR build ----------
__global__ void k_hist(const int* dst, unsigned* hist) {
  int e = blockIdx.x * blockDim.x + threadIdx.x;
  if (e < EE) atomicAdd(&hist[dst[e]], 1u);
}
__global__ __launch_bounds__(1024) void k_scan1(const unsigned* hist, unsigned* rowptr,
                                                unsigned* part) {
  __shared__ unsigned sc[1024];
  int t = threadIdx.x;
  int i = blockIdx.x * 1024 + t;
  unsigned v = (i < NN) ? hist[i] : 0u;
  sc[t] = v;
  __syncthreads();
  for (int o = 1; o < 1024; o <<= 1) {
    unsigned add = (t >= o) ? sc[t - o] : 0u;
    __syncthreads();
    sc[t] += add;
    __syncthreads();
  }
  if (i < NN) rowptr[i] = sc[t] - v;  // exclusive
  if (t == 1023) part[blockIdx.x] = sc[1023];
}
__global__ void k_scan2(unsigned* part) {
  if (threadIdx.x == 0) {
    unsigned run = 0;
    for (int b = 0; b < NB1; b++) { unsigned t = part[b]; part[b] = run; run += t; }
  }
}
__global__ void k_scan3(unsigned* rowptr, const unsigned* part, unsigned* cursor) {
  int i = blockIdx.x * blockDim.x + threadIdx.x;
  if (i < NN) {
    unsigned r = rowptr[i] + part[i >> 10];
    rowptr[i] = r;
    cursor[i] = r;
  }
  if (i == 0) rowptr[NN] = EE;
}
// scatter: one interleaved 32B record per permuted edge
__global__ void k_scatter(const int* src, const int* dst, const float* ea,
                          const float* V1, const float* V2, unsigned* cursor,
                          PEdge* ep) {
  int e = blockIdx.x * blockDim.x + threadIdx.x;
  if (e >= EE) return;
  int d = dst[e];
  unsigned pos = atomicAdd(&cursor[d], 1u);
  float av[5];
#pragma unroll
  for (int k = 0; k < 5; k++) av[k] = ea[(size_t)e * 5 + k];
  float a2 = 0.f;
#pragma unroll
  for (int k = 0; k < 5; k++) a2 = fmaf(av[k], V2[k], a2);
  unsigned short hb[8];
#pragma unroll
  for (int hh = 0; hh < 8; hh++) {
    float a1 = 0.f;
#pragma unroll
    for (int k = 0; k < 5; k++) a1 = fmaf(av[k], V1[k * 8 + hh], a1);
    hb[hh] = f2h(a1);
  }
  uint4 w0, w1;
  w0.x = (unsigned)src[e];
  w0.y = __float_as_uint(a2);
  w0.z = (unsigned)hb[0] | ((unsigned)hb[1] << 16);
  w0.w = (unsigned)hb[2] | ((unsigned)hb[3] << 16);
  w1.x = (unsigned)hb[4] | ((unsigned)hb[5] << 16);
  w1.y = (unsigned)hb[6] | ((unsigned)hb[7] << 16);
  w1.z = 0u; w1.w = 0u;
  uint4* p = (uint4*)(ep + pos);
  p[0] = w0;
  p[1] = w1;
}

// ---------- K3: MFMA xw1(bf16) = x(bf16)@W1 [N,256] ----------
__global__ __launch_bounds__(256) void k_gemm1(const unsigned short* x,
                                               const unsigned short* W1t,
                                               unsigned short* xw1) {
  __shared__ char wlds[65536];
  int tid = threadIdx.x;
#pragma unroll
  for (int it = 0; it < 16; it++) {
    int cch = it * 256 + tid;
    int row = cch >> 4, seg = cch & 15;
    uint4 v = *(const uint4*)(W1t + row * 128 + seg * 8);
    *(uint4*)(&wlds[(row * 256 + seg * 16) ^ ((row & 7) << 4)]) = v;
  }
  __syncthreads();
  int wid = tid >> 6, l = tid & 63;
  int cl = l & 15, kh = l >> 4;
  int swz = (cl & 7) << 4;
  long r0 = (long)blockIdx.x * 128 + wid * 32;
  f32x4 acc[2][16];
#pragma unroll
  for (int rt = 0; rt < 2; rt++)
#pragma unroll
    for (int nt = 0; nt < 16; nt++) acc[rt][nt] = {0.f, 0.f, 0.f, 0.f};
  long ra0 = r0 + cl; if (ra0 > NN - 1) ra0 = NN - 1;
  long ra1 = r0 + 16 + cl; if (ra1 > NN - 1) ra1 = NN - 1;
#pragma unroll
  for (int kk = 0; kk < 4; kk++) {
    bf16x8 a0 = *(const bf16x8*)(x + ra0 * 128 + kk * 32 + kh * 8);
    bf16x8 a1 = *(const bf16x8*)(x + ra1 * 128 + kk * 32 + kh * 8);
#pragma unroll
    for (int nt = 0; nt < 16; nt++) {
      bf16x8 b = *(const bf16x8*)(&wlds[(((nt * 16 + cl) * 256) + kk * 64 + kh * 16) ^ swz]);
      acc[0][nt] = __builtin_amdgcn_mfma_f32_16x16x32_bf16(a0, b, acc[0][nt], 0, 0, 0);
      acc[1][nt] = __builtin_amdgcn_mfma_f32_16x16x32_bf16(a1, b, acc[1][nt], 0, 0, 0);
    }
  }
#pragma unroll
  for (int rt = 0; rt < 2; rt++)
#pragma unroll
    for (int nt = 0; nt < 16; nt++)
#pragma unroll
      for (int j = 0; j < 4; j++) {
        long row = r0 + rt * 16 + kh * 4 + j;
        if (row < NN) xw1[row * 256 + nt * 16 + cl] = f2bf(acc[rt][nt][j]);
      }
}

// ---------- K3b: al_s1/al_d1 from xw1 (wave per node, 8-lane head groups) ----------
__global__ __launch_bounds__(256) void k_al(const unsigned short* xw1, const float* as1,
                                            const float* ad1, float* al_s1,
                                            float* al_d1) {
  int w = threadIdx.x >> 6, lane = threadIdx.x & 63;
  int i = blockIdx.x * 4 + w;
  if (i >= NN) return;
  ushort4 xv = ((const ushort4*)(xw1 + (size_t)i * 256))[lane];
  float4 as = ((const float4*)as1)[lane];
  float4 ad = ((const float4*)ad1)[lane];
  float x0 = bf2f(xv.x), x1 = bf2f(xv.y), x2 = bf2f(xv.z), x3 = bf2f(xv.w);
  float s = x0 * as.x + x1 * as.y + x2 * as.z + x3 * as.w;
  float d = x0 * ad.x + x1 * ad.y + x2 * ad.z + x3 * ad.w;
#pragma unroll
  for (int o = 1; o < 8; o <<= 1) {
    s += __shfl_xor(s, o);
    d += __shfl_xor(d, o);
  }
  if ((lane & 7) == 0) {
    al_s1[i * 8 + (lane >> 3)] = s;
    al_d1[i * 8 + (lane >> 3)] = d;
  }
}

// ---------- K5: MFMA xw2(bf16) = h(bf16)@W2 [N,128] ----------
__global__ __launch_bounds__(256) void k_gemm2(const unsigned short* h,
                                               const unsigned short* W2t,
                                               unsigned short* xw2) {
  __shared__ char wlds[65536];
  int tid = threadIdx.x;
#pragma unroll
  for (int it = 0; it < 16; it++) {
    int cch = it * 256 + tid;
    int row = cch >> 5, seg = cch & 31;
    uint4 v = *(const uint4*)(W2t + row * 256 + seg * 8);
    *(uint4*)(&wlds[(row * 512 + seg * 16) ^ ((row & 7) << 4)]) = v;
  }
  __syncthreads();
  int wid = tid >> 6, l = tid & 63;
  int cl = l & 15, kh = l >> 4;
  int swz = (cl & 7) << 4;
  long r0 = (long)blockIdx.x * 128 + wid * 32;
  f32x4 acc[2][8];
#pragma unroll
  for (int rt = 0; rt < 2; rt++)
#pragma unroll
    for (int nt = 0; nt < 8; nt++) acc[rt][nt] = {0.f, 0.f, 0.f, 0.f};
  long ra0 = r0 + cl; if (ra0 > NN - 1) ra0 = NN - 1;
  long ra1 = r0 + 16 + cl; if (ra1 > NN - 1) ra1 = NN - 1;
#pragma unroll
  for (int kk = 0; kk < 8; kk++) {
    bf16x8 a0 = *(const bf16x8*)(h + ra0 * 256 + kk * 32 + kh * 8);
    bf16x8 a1 = *(const bf16x8*)(h + ra1 * 256 + kk * 32 + kh * 8);
#pragma unroll
    for (int nt = 0; nt < 8; nt++) {
      bf16x8 b = *(const bf16x8*)(&wlds[(((nt * 16 + cl) * 512) + kk * 64 + kh * 16) ^ swz]);
      acc[0][nt] = __builtin_amdgcn_mfma_f32_16x16x32_bf16(a0, b, acc[0][nt], 0, 0, 0);
      acc[1][nt] = __builtin_amdgcn_mfma_f32_16x16x32_bf16(a1, b, acc[1][nt], 0, 0, 0);
    }
  }
#pragma unroll
  for (int rt = 0; rt < 2; rt++)
#pragma unroll
    for (int nt = 0; nt < 8; nt++)
#pragma unroll
      for (int j = 0; j < 4; j++) {
        long row = r0 + rt * 16 + kh * 4 + j;
        if (row < NN) xw2[row * 128 + nt * 16 + cl] = f2bf(acc[rt][nt][j]);
      }
}

// ---------- K4: layer-1 GAT, wave per dst node, chunked two-phase softmax ----------
__global__ __launch_bounds__(256) void k_gat1(
    const unsigned* rowptr, const PEdge* ep, const float* al_s1, const float* al_d1,
    const unsigned short* xw1, const float* b1, const float* us2, const float* ud2,
    unsigned short* h, float* al_s2, float* al_d2) {
  int w = threadIdx.x >> 6, lane = threadIdx.x & 63;
  int i = blockIdx.x * 4 + w;
  if (i >= NN) return;
  int r0 = rowptr[i], r1 = rowptr[i + 1];
  int hh = lane & 7;   // head (pass A)
  int js = lane >> 3;  // edge-sub (pass A)
  int ah = lane >> 3;  // head owning channels lane*4..lane*4+3 (pass B)
  float ald = al_d1[i * 8 + hh];
  float m = -1e30f, l = 0.f;
  float a0 = 0.f, a1 = 0.f, a2 = 0.f, a3 = 0.f;
  float alesum = 0.f;

  auto chunk = [&](int jb, int cnt) {
    bool valid = js < cnt;
    int jc = jb + (valid ? js : cnt - 1);
    int s = ((const int*)&ep[jc])[0];
    float ale = h2f(((const unsigned short*)&ep[jc])[4 + hh]);
    if (!valid) ale = 0.f;
    alesum += ale;
    float logit = -1e30f;
    if (valid) {
      float al = al_s1[s * 8 + hh] + ald + ale;
      logit = al > 0.f ? al : 0.2f * al;
    }
    float cm = logit;
    cm = fmaxf(cm, __shfl_xor(cm, 8));
    cm = fmaxf(cm, __shfl_xor(cm, 16));
    cm = fmaxf(cm, __shfl_xor(cm, 32));
    float mn = fmaxf(m, cm);
    float sc = __expf(m - mn);
    float p = __expf(logit - mn);
    float ps = p;
    ps += __shfl_xor(ps, 8);
    ps += __shfl_xor(ps, 16);
    ps += __shfl_xor(ps, 32);
    l = l * sc + ps;
    m = mn;
    float asc = __shfl(sc, ah);
    a0 *= asc; a1 *= asc; a2 *= asc; a3 *= asc;
    for (int jj = 0; jj < cnt; jj++) {
      float pj = __shfl(p, jj * 8 + ah);
      int sj = __shfl(s, jj * 8);
      ushort4 xv = ((const ushort4*)(xw1 + (size_t)sj * 256))[lane];
      a0 = fmaf(pj, bf2f(xv.x), a0);
      a1 = fmaf(pj, bf2f(xv.y), a1);
      a2 = fmaf(pj, bf2f(xv.z), a2);
      a3 = fmaf(pj, bf2f(xv.w), a3);
    }
  };
  int jb = r0;
  for (; jb + 8 <= r1; jb += 8) chunk(jb, 8);
  if (jb < r1) chunk(jb, r1 - jb);

  // self-loop (edge_attr = mean of incoming per-edge ale, by linearity)
  alesum += __shfl_xor(alesum, 8);
  alesum += __shfl_xor(alesum, 16);
  alesum += __shfl_xor(alesum, 32);
  float inv = 1.f / fmaxf((float)(r1 - r0), 1.f);
  float aleS = alesum * inv;
  {
    float al = al_s1[i * 8 + hh] + ald + aleS;
    float logit = al > 0.f ? al : 0.2f * al;
    float mn = fmaxf(m, logit);
    float sc = __expf(m - mn);
    float p = __expf(logit - mn);
    l = l * sc + p;
    m = mn;
    float asc = __shfl(sc, ah);
    float pj = __shfl(p, ah);
    ushort4 xv = ((const ushort4*)(xw1 + (size_t)i * 256))[lane];
    a0 = fmaf(pj, bf2f(xv.x), a0 * asc);
    a1 = fmaf(pj, bf2f(xv.y), a1 * asc);
    a2 = fmaf(pj, bf2f(xv.z), a2 * asc);
    a3 = fmaf(pj, bf2f(xv.w), a3 * asc);
  }
  // finalize: /l + b1, elu
  float lh = __shfl(l, ah);
  float invl = 1.f / (lh + 1e-16f);
  float4 bv = ((const float4*)b1)[lane];
  float v0 = a0 * invl + bv.x, v1 = a1 * invl + bv.y;
  float v2 = a2 * invl + bv.z, v3 = a3 * invl + bv.w;
  v0 = v0 > 0.f ? v0 : expm1f(v0);
  v1 = v1 > 0.f ? v1 : expm1f(v1);
  v2 = v2 > 0.f ? v2 : expm1f(v2);
  v3 = v3 > 0.f ? v3 : expm1f(v3);
  ushort4 hv;
  hv.x = f2bf(v0); hv.y = f2bf(v1); hv.z = f2bf(v2); hv.w = f2bf(v3);
  ((ushort4*)(h + (size_t)i * 256))[lane] = hv;
  // layer-2 logit pieces
  float4 uv = ((const float4*)us2)[lane];
  float4 dv = ((const float4*)ud2)[lane];
  float ps2 = v0 * uv.x + v1 * uv.y + v2 * uv.z + v3 * uv.w;
  float pd2 = v0 * dv.x + v1 * dv.y + v2 * dv.z + v3 * dv.w;
  ps2 = wave_sum(ps2);
  pd2 = wave_sum(pd2);
  if (lane == 0) { al_s2[i] = ps2; al_d2[i] = pd2; }
}

// ---------- K6: layer-2 GAT, wave per dst node, chunked two-phase softmax ----------
__global__ __launch_bounds__(256) void k_gat2(
    const unsigned* rowptr, const PEdge* ep, const float* al_s2, const float* al_d2,
    const unsigned short* xw2, const float* b2, float* out) {
  int w = threadIdx.x >> 6, lane = threadIdx.x & 63;
  int i = blockIdx.x * 4 + w;
  if (i >= NN) return;
  int r0 = rowptr[i], r1 = rowptr[i + 1];
  float ald = al_d2[i];
  float m = -1e30f, l = 0.f, a0 = 0.f, a1 = 0.f;
  float alesum = 0.f;

  auto chunk = [&](int jb, int cnt) {
    bool valid = lane < cnt;
    int jc = jb + (valid ? lane : cnt - 1);
    int2 sv = *(const int2*)&ep[jc];
    int s = sv.x;
    float ale = valid ? __uint_as_float((unsigned)sv.y) : 0.f;
    alesum += ale;
    float logit = -1e30f;
    if (valid) {
      float al = al_s2[s] + ald + ale;
      logit = al > 0.f ? al : 0.2f * al;
    }
    float cm = wave_max(logit);
    float mn = fmaxf(m, cm);
    float sc = __expf(m - mn);
    float p = __expf(logit - mn);
    float ps = wave_sum(p);
    l = l * sc + ps;
    m = mn;
    a0 *= sc; a1 *= sc;
    for (int jj = 0; jj < cnt; jj++) {
      float pj = __shfl(p, jj);
      int sj = __shfl(s, jj);
      ushort2 xv = ((const ushort2*)(xw2 + (size_t)sj * 128))[lane];
      a0 = fmaf(pj, bf2f(xv.x), a0);
      a1 = fmaf(pj, bf2f(xv.y), a1);
    }
  };
  int jb = r0;
  for (; jb + 64 <= r1; jb += 64) chunk(jb, 64);
  if (jb < r1) chunk(jb, r1 - jb);

  // self-loop
  alesum = wave_sum(alesum);
  float inv = 1.f / fmaxf((float)(r1 - r0), 1.f);
  float aleS = alesum * inv;
  {
    float al = al_s2[i] + ald + aleS;
    float logit = al > 0.f ? al : 0.2f * al;
    float mn = fmaxf(m, logit);
    float sc = __expf(m - mn);
    float p = __expf(logit - mn);
    l = l * sc + p;
    ushort2 xv = ((const ushort2*)(xw2 + (size_t)i * 128))[lane];
    a0 = fmaf(p, bf2f(xv.x), a0 * sc);
    a1 = fmaf(p, bf2f(xv.y), a1 * sc);
  }
  float invl = 1.f / (l + 1e-16f);
  float2 bv = ((const float2*)b2)[lane];
  float2 ov = {a0 * invl + bv.x, a1 * invl + bv.y};
  ((float2*)(out + (size_t)i * 128))[lane] = ov;
}

extern "C" void kernel_launch(void* const* d_in, const int* in_sizes, int n_in,
                              void* d_out, int out_size, void* d_ws, size_t ws_size,
                              hipStream_t stream) {
  const float* pol_feat = (const float*)d_in[0];
  const int* state_ids = (const int*)d_in[1];
  const int* comp_cat = (const int*)d_in[2];
  const float* comp_price = (const float*)d_in[3];
  const int* edge_index = (const int*)d_in[4];
  const float* edge_attr = (const float*)d_in[5];
  const float* Wp = (const float*)d_in[6];
  const float* bp = (const float*)d_in[7];
  const float* state_emb = (const float*)d_in[8];
  const float* sector_emb = (const float*)d_in[9];
  const float* industry_emb = (const float*)d_in[10];
  const float* Wc = (const float*)d_in[11];
  const float* bc = (const float*)d_in[12];
  const float* ln_g = (const float*)d_in[13];
  const float* ln_b = (const float*)d_in[14];
  const float* W1 = (const float*)d_in[15];
  const float* as1 = (const float*)d_in[16];
  const float* ad1 = (const float*)d_in[17];
  const float* We1 = (const float*)d_in[18];
  const float* ae1 = (const float*)d_in[19];
  const float* b1 = (const float*)d_in[20];
  const float* W2 = (const float*)d_in[21];
  const float* as2 = (const float*)d_in[22];
  const float* ad2 = (const float*)d_in[23];
  const float* We2 = (const float*)d_in[24];
  const float* ae2 = (const float*)d_in[25];
  const float* b2 = (const float*)d_in[26];
  const int* srcv = edge_index;
  const int* dstv = edge_index + EE;
  float* out = (float*)d_out;

  // ---- workspace layout (aliased; peak ~143 MiB) ----
  size_t off = 0;
  auto alloc = [&](size_t nbytes) -> char* {
    char* p = (char*)d_ws + off;
    off += ((nbytes + 255) & ~(size_t)255);
    return p;
  };
  // region A: xw1 (bf16, NN*256*2); xw2 (bf16, NN*128*2) reuses it after gat1
  char* regA = alloc((size_t)NN * 512);
  // region B: h (bf16, NN*256*2); x (bf16, NN*128*2) occupies first half (dead after gemm1)
  char* regB = alloc((size_t)NN * 512);
  unsigned short* xw1 = (unsigned short*)regA;
  unsigned short* xw2 = (unsigned short*)regA;
  unsigned short* h = (unsigned short*)regB;
  unsigned short* x = (unsigned short*)regB;
  float* al_s1 = (float*)alloc((size_t)NN * 8 * 4);
  float* al_d1 = (float*)alloc((size_t)NN * 8 * 4);
  float* al_s2 = (float*)alloc((size_t)NN * 4);
  float* al_d2 = (float*)alloc((size_t)NN * 4);
  float* us2 = (float*)alloc(256 * 4);
  float* ud2 = (float*)alloc(256 * 4);
  float* V1 = (float*)alloc(64 * 4);
  float* V2 = (float*)alloc(8 * 4);
  unsigned short* W1t = (unsigned short*)alloc(32768 * 2);
  unsigned short* W2t = (unsigned short*)alloc(32768 * 2);
  unsigned* hist = (unsigned*)alloc((size_t)NN * 4);
  unsigned* rowptr = (unsigned*)alloc((size_t)(NN + 1) * 4);
  unsigned* cursor = (unsigned*)alloc((size_t)NN * 4);
  unsigned* part = (unsigned*)alloc((size_t)NB1 * 4);
  PEdge* ep = (PEdge*)alloc((size_t)EE * sizeof(PEdge));

  hipMemsetAsync(hist, 0, (size_t)NN * 4, stream);

  k_pre<<<1, 256, 0, stream>>>(W2, as2, ad2, We1, ae1, We2, ae2, us2, ud2, V1, V2);
  k_prew<<<256, 256, 0, stream>>>(W1, W2, W1t, W2t);
  k_encode<<<NN / 2, 256, 0, stream>>>(pol_feat, state_ids, comp_cat, comp_price, Wp,
                                       bp, state_emb, sector_emb, industry_emb, Wc, bc,
                                       ln_g, ln_b, x);
  k_hist<<<(EE + 255) / 256, 256, 0, stream>>>(dstv, hist);
  k_scan1<<<NB1, 1024, 0, stream>>>(hist, rowptr, part);
  k_scan2<<<1, 64, 0, stream>>>(part);
  k_scan3<<<(NN + 255) / 256, 256, 0, stream>>>(rowptr, part, cursor);
  k_scatter<<<(EE + 255) / 256, 256, 0, stream>>>(srcv, dstv, edge_attr, V1, V2,
                                                  cursor, ep);
  k_gemm1<<<(NN + 127) / 128, 256, 0, stream>>>(x, W1t, xw1);
  k_al<<<NN / 4, 256, 0, stream>>>(xw1, as1, ad1, al_s1, al_d1);
  k_gat1<<<NN / 4, 256, 0, stream>>>(rowptr, ep, al_s1, al_d1, xw1, b1, us2, ud2, h,
                                     al_s2, al_d2);
  k_gemm2<<<(NN + 127) / 128, 256, 0, stream>>>(h, W2t, xw2);
  k_gat2<<<NN / 4, 256, 0, stream>>>(rowptr, ep, al_s2, al_d2, xw2, b2, out);
}